// Round 1
// baseline (242.737 us; speedup 1.0000x reference)
//
#include <hip/hip_runtime.h>

typedef unsigned short u16;
typedef __attribute__((ext_vector_type(8))) __bf16 bf16x8;
typedef __attribute__((ext_vector_type(4))) float f32x4;

struct alignas(8) U16x4 { u16 x, y, z, w; };

__device__ __forceinline__ u16 f2bf(float f) {
    union { float f; unsigned u; } v; v.f = f;
    unsigned r = v.u + 0x7fffu + ((v.u >> 16) & 1u);
    return (u16)(r >> 16);
}

__device__ __forceinline__ void gload_lds16(const void* g, void* l) {
    __builtin_amdgcn_global_load_lds(
        (__attribute__((address_space(1))) void*)g,
        (__attribute__((address_space(3))) void*)l, 16, 0, 0);
}

// ---------------------------------------------------------------------------
// LayerNorm: one wave per row (D=1024). Writes optional f32 copy + bf16 copy.
// ---------------------------------------------------------------------------
__global__ __launch_bounds__(256)
void ln_fused(const float* __restrict__ x, const float* __restrict__ g,
              const float* __restrict__ be, float* __restrict__ y32,
              u16* __restrict__ y16)
{
    const int wid = threadIdx.x >> 6, lane = threadIdx.x & 63;
    const size_t row = (size_t)blockIdx.x * 4 + wid;
    const float4* xr = (const float4*)(x + row * 1024);
    float4 v[4];
    float s = 0.f, ss = 0.f;
#pragma unroll
    for (int i = 0; i < 4; ++i) {
        v[i] = xr[i * 64 + lane];
        s  += (v[i].x + v[i].y) + (v[i].z + v[i].w);
        ss += (v[i].x * v[i].x + v[i].y * v[i].y) + (v[i].z * v[i].z + v[i].w * v[i].w);
    }
#pragma unroll
    for (int o = 32; o; o >>= 1) { s += __shfl_xor(s, o, 64); ss += __shfl_xor(ss, o, 64); }
    const float mu = s * (1.f / 1024.f);
    const float rstd = rsqrtf(ss * (1.f / 1024.f) - mu * mu + 1e-5f);
#pragma unroll
    for (int i = 0; i < 4; ++i) {
        float4 gv = ((const float4*)g)[i * 64 + lane];
        float4 bv = ((const float4*)be)[i * 64 + lane];
        float4 o;
        o.x = (v[i].x - mu) * rstd * gv.x + bv.x;
        o.y = (v[i].y - mu) * rstd * gv.y + bv.y;
        o.z = (v[i].z - mu) * rstd * gv.z + bv.z;
        o.w = (v[i].w - mu) * rstd * gv.w + bv.w;
        if (y32) ((float4*)(y32 + row * 1024))[i * 64 + lane] = o;
        U16x4 pk = { f2bf(o.x), f2bf(o.y), f2bf(o.z), f2bf(o.w) };
        ((U16x4*)(y16 + row * 1024))[i * 64 + lane] = pk;
    }
}

// ---------------------------------------------------------------------------
// Weight conversion f32 -> bf16 for all four projection matrices.
// ---------------------------------------------------------------------------
__global__ __launch_bounds__(256)
void wconv4(const float4* __restrict__ a, const float4* __restrict__ b,
            const float4* __restrict__ c, const float4* __restrict__ d,
            U16x4* __restrict__ oa, U16x4* __restrict__ ob,
            U16x4* __restrict__ oc, U16x4* __restrict__ od)
{
    const int i = blockIdx.x * 256 + threadIdx.x;
    float4 v;
    v = a[i]; oa[i] = { f2bf(v.x), f2bf(v.y), f2bf(v.z), f2bf(v.w) };
    v = b[i]; ob[i] = { f2bf(v.x), f2bf(v.y), f2bf(v.z), f2bf(v.w) };
    v = c[i]; oc[i] = { f2bf(v.x), f2bf(v.y), f2bf(v.z), f2bf(v.w) };
    v = d[i]; od[i] = { f2bf(v.x), f2bf(v.y), f2bf(v.z), f2bf(v.w) };
}

// ---------------------------------------------------------------------------
// GEMM: C[m,n] = (sum_k A[m,k] * W[n,k] + bias[n]) * alpha  (+ resid, MODE 1)
// A: bf16 [M,K] row-major. W: bf16 [N,K] row-major (torch Linear layout).
// MODE 0: bf16 out [M,N].  MODE 1: f32 out [M,N] + f32 residual.
// MODE 2: bf16 out transposed for V: [(m>>12)*1024 + n][m & 4095] (B,H*64,Nc).
// 128x128 tile, BK=64, 4 waves (2x2 of 64x64), global_load_lds staging.
// ---------------------------------------------------------------------------
template<int MODE>
__global__ __launch_bounds__(256)
void gemm_bt(const u16* __restrict__ A, const u16* __restrict__ W,
             const float* __restrict__ bias, const float* __restrict__ resid,
             void* __restrict__ Cp, int M, int N, int K, float alpha)
{
    constexpr int BK = 64;
    __shared__ __align__(16) u16 sA[128 * BK];
    __shared__ __align__(16) u16 sB[128 * BK];
    const int tid = threadIdx.x, wid = tid >> 6, lane = tid & 63;
    const int lr = lane & 15, lg = lane >> 4;
    const int wr = wid >> 1, wc = wid & 1;
    const int row0 = blockIdx.x * 128, col0 = blockIdx.y * 128;
    const int srow = wid * 8 + (lane >> 3), scol = (lane & 7) * 8;

    const u16* Ag = A + (size_t)(row0 + srow) * K + scol;
    const u16* Wg = W + (size_t)(col0 + srow) * K + scol;

    f32x4 acc[4][4];
#pragma unroll
    for (int m = 0; m < 4; ++m)
#pragma unroll
        for (int n = 0; n < 4; ++n) acc[m][n] = (f32x4){0.f, 0.f, 0.f, 0.f};

    for (int k0 = 0; k0 < K; k0 += BK) {
        __syncthreads();
#pragma unroll
        for (int i = 0; i < 4; ++i)
            gload_lds16(Ag + (size_t)i * 32 * K + k0, (char*)sA + i * 4096 + wid * 1024);
#pragma unroll
        for (int i = 0; i < 4; ++i)
            gload_lds16(Wg + (size_t)i * 32 * K + k0, (char*)sB + i * 4096 + wid * 1024);
        __syncthreads();
#pragma unroll
        for (int kk = 0; kk < 2; ++kk) {
            bf16x8 af[4], bfr[4];
#pragma unroll
            for (int m = 0; m < 4; ++m)
                af[m] = *(const bf16x8*)&sA[(wr * 64 + m * 16 + lr) * BK + kk * 32 + lg * 8];
#pragma unroll
            for (int n = 0; n < 4; ++n)
                bfr[n] = *(const bf16x8*)&sB[(wc * 64 + n * 16 + lr) * BK + kk * 32 + lg * 8];
#pragma unroll
            for (int m = 0; m < 4; ++m)
#pragma unroll
                for (int n = 0; n < 4; ++n)
                    acc[m][n] = __builtin_amdgcn_mfma_f32_16x16x32_bf16(af[m], bfr[n], acc[m][n], 0, 0, 0);
        }
    }

#pragma unroll
    for (int m = 0; m < 4; ++m) {
#pragma unroll
        for (int n = 0; n < 4; ++n) {
            const int r = row0 + wr * 64 + m * 16 + lg * 4;
            const int c = col0 + wc * 64 + n * 16 + lr;
            const float bv = bias[c];
            if constexpr (MODE == 0) {
                u16* C = (u16*)Cp;
#pragma unroll
                for (int j = 0; j < 4; ++j)
                    C[(size_t)(r + j) * N + c] = f2bf((acc[m][n][j] + bv) * alpha);
            } else if constexpr (MODE == 1) {
                float* C = (float*)Cp;
#pragma unroll
                for (int j = 0; j < 4; ++j)
                    C[(size_t)(r + j) * N + c] =
                        (acc[m][n][j] + bv) * alpha + resid[(size_t)(r + j) * N + c];
            } else {
                // transposed V write: row' = (r>>12)*1024 + c, col' = r & 4095
                u16* C = (u16*)Cp;
                const size_t base = ((size_t)(r >> 12) * 1024 + c) * 4096 + (r & 4095);
                U16x4 pk = { f2bf((acc[m][n][0] + bv) * alpha),
                             f2bf((acc[m][n][1] + bv) * alpha),
                             f2bf((acc[m][n][2] + bv) * alpha),
                             f2bf((acc[m][n][3] + bv) * alpha) };
                *(U16x4*)&C[base] = pk;
            }
        }
    }
}

// ---------------------------------------------------------------------------
// Flash cross-attention. Grid (Nq/64, H, B), 256 threads = 4 waves.
// Wave w owns 16 q-rows. Swapped QK^T: S^T = mfma(K, Q) so softmax over kv is
// register-local + 2 shfl_xor. P goes through a per-wave padded LDS strip,
// PV = mfma(V^T, P^T) accumulates out^T. Q is pre-scaled by 1/8 in its GEMM.
// ---------------------------------------------------------------------------
__global__ __launch_bounds__(256)
void attn_fwd(const u16* __restrict__ Q, const u16* __restrict__ Kg,
              const u16* __restrict__ Vt, u16* __restrict__ O)
{
    constexpr int D = 1024, LDP = 72;
    __shared__ __align__(16) u16 sK[64 * 64];
    __shared__ __align__(16) u16 sV[64 * 64];   // V^T tile: [d][kv]
    __shared__ __align__(16) u16 sP[4 * 16 * LDP];
    const int tid = threadIdx.x, wid = tid >> 6, lane = tid & 63;
    const int lr = lane & 15, lg = lane >> 4;
    const int b = blockIdx.z, h = blockIdx.y;
    const int q0 = blockIdx.x * 64 + wid * 16;
    const int srow = wid * 8 + (lane >> 3), scol = (lane & 7) * 8;

    const u16* Qrow = Q + (size_t)(b * 1024 + q0 + lr) * D + h * 64;
    const bf16x8 qf0 = *(const bf16x8*)(Qrow + lg * 8);
    const bf16x8 qf1 = *(const bf16x8*)(Qrow + 32 + lg * 8);

    const u16* Kst = Kg + (size_t)(b * 4096 + srow) * D + h * 64 + scol;
    const u16* Vst = Vt + ((size_t)(b * 16 + h) * 64 + srow) * 4096 + scol;
    u16* sPw = sP + wid * 16 * LDP;

    f32x4 po[4];
#pragma unroll
    for (int df = 0; df < 4; ++df) po[df] = (f32x4){0.f, 0.f, 0.f, 0.f};
    float m = -INFINITY, l = 0.f;

    for (int kv0 = 0; kv0 < 4096; kv0 += 64) {
        __syncthreads();
        gload_lds16(Kst + (size_t)kv0 * D,        (char*)sK + wid * 1024);
        gload_lds16(Kst + (size_t)(kv0 + 32) * D, (char*)sK + 4096 + wid * 1024);
        gload_lds16(Vst + kv0,                    (char*)sV + wid * 1024);
        gload_lds16(Vst + (size_t)32 * 4096 + kv0,(char*)sV + 4096 + wid * 1024);
        __syncthreads();

        // S^T[kv][q] = K . Q^T   (Q pre-scaled by 1/8)
        f32x4 s4[4];
#pragma unroll
        for (int f = 0; f < 4; ++f) {
            bf16x8 k0v = *(const bf16x8*)&sK[(f * 16 + lr) * 64 + lg * 8];
            bf16x8 k1v = *(const bf16x8*)&sK[(f * 16 + lr) * 64 + 32 + lg * 8];
            f32x4 z = (f32x4){0.f, 0.f, 0.f, 0.f};
            z = __builtin_amdgcn_mfma_f32_16x16x32_bf16(k0v, qf0, z, 0, 0, 0);
            s4[f] = __builtin_amdgcn_mfma_f32_16x16x32_bf16(k1v, qf1, z, 0, 0, 0);
        }

        // online softmax (lane holds kv = 16f + 4*lg + j for q-col = lr)
        float tmax = s4[0][0];
#pragma unroll
        for (int f = 0; f < 4; ++f) {
            tmax = fmaxf(tmax, s4[f][0]); tmax = fmaxf(tmax, s4[f][1]);
            tmax = fmaxf(tmax, s4[f][2]); tmax = fmaxf(tmax, s4[f][3]);
        }
        tmax = fmaxf(tmax, __shfl_xor(tmax, 16, 64));
        tmax = fmaxf(tmax, __shfl_xor(tmax, 32, 64));
        const float mn = fmaxf(m, tmax);
        const float corr = __expf(m - mn);
        float lsum = 0.f;
        U16x4 pk[4];
#pragma unroll
        for (int f = 0; f < 4; ++f) {
            float p0 = __expf(s4[f][0] - mn);
            float p1 = __expf(s4[f][1] - mn);
            float p2 = __expf(s4[f][2] - mn);
            float p3 = __expf(s4[f][3] - mn);
            lsum += (p0 + p1) + (p2 + p3);
            pk[f] = { f2bf(p0), f2bf(p1), f2bf(p2), f2bf(p3) };
        }
        lsum += __shfl_xor(lsum, 16, 64);
        lsum += __shfl_xor(lsum, 32, 64);
        l = l * corr + lsum;
#pragma unroll
        for (int df = 0; df < 4; ++df) po[df] *= corr;
        m = mn;

        // P[q][kv] to per-wave LDS strip (no barrier: wave-private, DS in-order)
#pragma unroll
        for (int f = 0; f < 4; ++f)
            *(U16x4*)&sPw[lr * LDP + f * 16 + lg * 4] = pk[f];

        // out^T[d][q] += V^T . P^T
#pragma unroll
        for (int c = 0; c < 2; ++c) {
            bf16x8 pf = *(const bf16x8*)&sPw[lr * LDP + c * 32 + lg * 8];
#pragma unroll
            for (int df = 0; df < 4; ++df) {
                bf16x8 vf = *(const bf16x8*)&sV[(df * 16 + lr) * 64 + c * 32 + lg * 8];
                po[df] = __builtin_amdgcn_mfma_f32_16x16x32_bf16(vf, pf, po[df], 0, 0, 0);
            }
        }
    }

    const float rl = 1.f / l;
    u16* Orow = O + (size_t)(b * 1024 + q0 + lr) * D + h * 64;
#pragma unroll
    for (int df = 0; df < 4; ++df) {
        U16x4 pk = { f2bf(po[df][0] * rl), f2bf(po[df][1] * rl),
                     f2bf(po[df][2] * rl), f2bf(po[df][3] * rl) };
        *(U16x4*)&Orow[df * 16 + lg * 4] = pk;
    }
}

// ---------------------------------------------------------------------------
extern "C" void kernel_launch(void* const* d_in, const int* in_sizes, int n_in,
                              void* d_out, int out_size, void* d_ws, size_t ws_size,
                              hipStream_t stream)
{
    const float* query   = (const float*)d_in[0];
    const float* context = (const float*)d_in[1];
    const float* wq = (const float*)d_in[2];
    const float* bq = (const float*)d_in[3];
    const float* wk = (const float*)d_in[4];
    const float* bk = (const float*)d_in[5];
    const float* wv = (const float*)d_in[6];
    const float* bv = (const float*)d_in[7];
    const float* wo = (const float*)d_in[8];
    const float* bo = (const float*)d_in[9];
    const float* g_q  = (const float*)d_in[10];
    const float* b_q  = (const float*)d_in[11];
    const float* g_kv = (const float*)d_in[12];
    const float* b_kv = (const float*)d_in[13];

    char* p = (char*)d_ws;
    auto alloc = [&](size_t bytes) { char* r = p; p += (bytes + 255) & ~(size_t)255; return r; };
    u16*   wqb  = (u16*)alloc(1024 * 1024 * 2);
    u16*   wkb  = (u16*)alloc(1024 * 1024 * 2);
    u16*   wvb  = (u16*)alloc(1024 * 1024 * 2);
    u16*   wob  = (u16*)alloc(1024 * 1024 * 2);
    float* qn32 = (float*)alloc((size_t)2048 * 1024 * 4);
    u16*   qnb  = (u16*)alloc((size_t)2048 * 1024 * 2);
    u16*   cnb  = (u16*)alloc((size_t)8192 * 1024 * 2);
    u16*   Qb   = (u16*)alloc((size_t)2048 * 1024 * 2);
    u16*   Kb   = (u16*)alloc((size_t)8192 * 1024 * 2);
    u16*   Vtb  = (u16*)alloc((size_t)8192 * 1024 * 2);
    u16*   AOb  = (u16*)alloc((size_t)2048 * 1024 * 2);

    wconv4<<<1024, 256, 0, stream>>>((const float4*)wq, (const float4*)wk,
                                     (const float4*)wv, (const float4*)wo,
                                     (U16x4*)wqb, (U16x4*)wkb, (U16x4*)wvb, (U16x4*)wob);
    ln_fused<<<512, 256, 0, stream>>>(query, g_q, b_q, qn32, qnb);
    ln_fused<<<2048, 256, 0, stream>>>(context, g_kv, b_kv, nullptr, cnb);

    // Q = (qn.wq^T + bq) * 0.125  (attention scale folded in)
    gemm_bt<0><<<dim3(16, 8), 256, 0, stream>>>(qnb, wqb, bq, nullptr, Qb, 2048, 1024, 1024, 0.125f);
    gemm_bt<0><<<dim3(64, 8), 256, 0, stream>>>(cnb, wkb, bk, nullptr, Kb, 8192, 1024, 1024, 1.0f);
    gemm_bt<2><<<dim3(64, 8), 256, 0, stream>>>(cnb, wvb, bv, nullptr, Vtb, 8192, 1024, 1024, 1.0f);

    attn_fwd<<<dim3(16, 16, 2), 256, 0, stream>>>(Qb, Kb, Vtb, AOb);

    // out = qn + AO.wo^T + bo   (f32 output, residual fused)
    gemm_bt<1><<<dim3(16, 8), 256, 0, stream>>>(AOb, wob, bo, qn32, d_out, 2048, 1024, 1024, 1.0f);
}

// Round 2
// 209.784 us; speedup vs baseline: 1.1571x; 1.1571x over previous
//
#include <hip/hip_runtime.h>

typedef unsigned short u16;
typedef __attribute__((ext_vector_type(8))) __bf16 bf16x8;
typedef __attribute__((ext_vector_type(4))) float f32x4;

struct alignas(8) U16x4 { u16 x, y, z, w; };

__device__ __forceinline__ u16 f2bf(float f) {
    union { float f; unsigned u; } v; v.f = f;
    unsigned r = v.u + 0x7fffu + ((v.u >> 16) & 1u);
    return (u16)(r >> 16);
}

__device__ __forceinline__ unsigned cvt_pk_bf16(float lo, float hi) {
    unsigned r;
    asm("v_cvt_pk_bf16_f32 %0, %1, %2" : "=v"(r) : "v"(lo), "v"(hi));
    return r;
}

__device__ __forceinline__ void gload_lds16(const void* g, void* l) {
    __builtin_amdgcn_global_load_lds(
        (__attribute__((address_space(1))) void*)g,
        (__attribute__((address_space(3))) void*)l, 16, 0, 0);
}

// ---------------------------------------------------------------------------
// LayerNorm: one wave per row (D=1024). Writes optional f32 copy + bf16 copy.
// ---------------------------------------------------------------------------
__global__ __launch_bounds__(256)
void ln_fused(const float* __restrict__ x, const float* __restrict__ g,
              const float* __restrict__ be, float* __restrict__ y32,
              u16* __restrict__ y16)
{
    const int wid = threadIdx.x >> 6, lane = threadIdx.x & 63;
    const size_t row = (size_t)blockIdx.x * 4 + wid;
    const float4* xr = (const float4*)(x + row * 1024);
    float4 v[4];
    float s = 0.f, ss = 0.f;
#pragma unroll
    for (int i = 0; i < 4; ++i) {
        v[i] = xr[i * 64 + lane];
        s  += (v[i].x + v[i].y) + (v[i].z + v[i].w);
        ss += (v[i].x * v[i].x + v[i].y * v[i].y) + (v[i].z * v[i].z + v[i].w * v[i].w);
    }
#pragma unroll
    for (int o = 32; o; o >>= 1) { s += __shfl_xor(s, o, 64); ss += __shfl_xor(ss, o, 64); }
    const float mu = s * (1.f / 1024.f);
    const float rstd = rsqrtf(ss * (1.f / 1024.f) - mu * mu + 1e-5f);
#pragma unroll
    for (int i = 0; i < 4; ++i) {
        float4 gv = ((const float4*)g)[i * 64 + lane];
        float4 bv = ((const float4*)be)[i * 64 + lane];
        float4 o;
        o.x = (v[i].x - mu) * rstd * gv.x + bv.x;
        o.y = (v[i].y - mu) * rstd * gv.y + bv.y;
        o.z = (v[i].z - mu) * rstd * gv.z + bv.z;
        o.w = (v[i].w - mu) * rstd * gv.w + bv.w;
        if (y32) ((float4*)(y32 + row * 1024))[i * 64 + lane] = o;
        U16x4 pk = { f2bf(o.x), f2bf(o.y), f2bf(o.z), f2bf(o.w) };
        ((U16x4*)(y16 + row * 1024))[i * 64 + lane] = pk;
    }
}

// ---------------------------------------------------------------------------
// Weight conversion f32 -> bf16 for all four projection matrices.
// ---------------------------------------------------------------------------
__global__ __launch_bounds__(256)
void wconv4(const float4* __restrict__ a, const float4* __restrict__ b,
            const float4* __restrict__ c, const float4* __restrict__ d,
            U16x4* __restrict__ oa, U16x4* __restrict__ ob,
            U16x4* __restrict__ oc, U16x4* __restrict__ od)
{
    const int i = blockIdx.x * 256 + threadIdx.x;
    float4 v;
    v = a[i]; oa[i] = { f2bf(v.x), f2bf(v.y), f2bf(v.z), f2bf(v.w) };
    v = b[i]; ob[i] = { f2bf(v.x), f2bf(v.y), f2bf(v.z), f2bf(v.w) };
    v = c[i]; oc[i] = { f2bf(v.x), f2bf(v.y), f2bf(v.z), f2bf(v.w) };
    v = d[i]; od[i] = { f2bf(v.x), f2bf(v.y), f2bf(v.z), f2bf(v.w) };
}

// ---------------------------------------------------------------------------
// GEMM: C[m,n] = (sum_k A[m,k] * W[n,k] + bias[n]) * alpha  (+ resid, MODE 1)
// A: bf16 [M,K] row-major. W: bf16 [N,K] row-major (torch Linear layout).
// MODE 0: bf16 out [M,N].  MODE 1: f32 out [M,N] + f32 residual.
// MODE 2: bf16 out transposed for V: [(m>>12)*1024 + n][m & 4095] (B,H*64,Nc).
// ---------------------------------------------------------------------------
template<int MODE>
__global__ __launch_bounds__(256)
void gemm_bt(const u16* __restrict__ A, const u16* __restrict__ W,
             const float* __restrict__ bias, const float* __restrict__ resid,
             void* __restrict__ Cp, int M, int N, int K, float alpha)
{
    constexpr int BK = 64;
    __shared__ __align__(16) u16 sA[128 * BK];
    __shared__ __align__(16) u16 sB[128 * BK];
    const int tid = threadIdx.x, wid = tid >> 6, lane = tid & 63;
    const int lr = lane & 15, lg = lane >> 4;
    const int wr = wid >> 1, wc = wid & 1;
    const int row0 = blockIdx.x * 128, col0 = blockIdx.y * 128;
    const int srow = wid * 8 + (lane >> 3), scol = (lane & 7) * 8;

    const u16* Ag = A + (size_t)(row0 + srow) * K + scol;
    const u16* Wg = W + (size_t)(col0 + srow) * K + scol;

    f32x4 acc[4][4];
#pragma unroll
    for (int m = 0; m < 4; ++m)
#pragma unroll
        for (int n = 0; n < 4; ++n) acc[m][n] = (f32x4){0.f, 0.f, 0.f, 0.f};

    for (int k0 = 0; k0 < K; k0 += BK) {
        __syncthreads();
#pragma unroll
        for (int i = 0; i < 4; ++i)
            gload_lds16(Ag + (size_t)i * 32 * K + k0, (char*)sA + i * 4096 + wid * 1024);
#pragma unroll
        for (int i = 0; i < 4; ++i)
            gload_lds16(Wg + (size_t)i * 32 * K + k0, (char*)sB + i * 4096 + wid * 1024);
        __syncthreads();
#pragma unroll
        for (int kk = 0; kk < 2; ++kk) {
            bf16x8 af[4], bfr[4];
#pragma unroll
            for (int m = 0; m < 4; ++m)
                af[m] = *(const bf16x8*)&sA[(wr * 64 + m * 16 + lr) * BK + kk * 32 + lg * 8];
#pragma unroll
            for (int n = 0; n < 4; ++n)
                bfr[n] = *(const bf16x8*)&sB[(wc * 64 + n * 16 + lr) * BK + kk * 32 + lg * 8];
#pragma unroll
            for (int m = 0; m < 4; ++m)
#pragma unroll
                for (int n = 0; n < 4; ++n)
                    acc[m][n] = __builtin_amdgcn_mfma_f32_16x16x32_bf16(af[m], bfr[n], acc[m][n], 0, 0, 0);
        }
    }

#pragma unroll
    for (int m = 0; m < 4; ++m) {
#pragma unroll
        for (int n = 0; n < 4; ++n) {
            const int r = row0 + wr * 64 + m * 16 + lg * 4;
            const int c = col0 + wc * 64 + n * 16 + lr;
            const float bv = bias[c];
            if constexpr (MODE == 0) {
                u16* C = (u16*)Cp;
#pragma unroll
                for (int j = 0; j < 4; ++j)
                    C[(size_t)(r + j) * N + c] = f2bf((acc[m][n][j] + bv) * alpha);
            } else if constexpr (MODE == 1) {
                float* C = (float*)Cp;
#pragma unroll
                for (int j = 0; j < 4; ++j)
                    C[(size_t)(r + j) * N + c] =
                        (acc[m][n][j] + bv) * alpha + resid[(size_t)(r + j) * N + c];
            } else {
                u16* C = (u16*)Cp;
                const size_t base = ((size_t)(r >> 12) * 1024 + c) * 4096 + (r & 4095);
                U16x4 pk = { f2bf((acc[m][n][0] + bv) * alpha),
                             f2bf((acc[m][n][1] + bv) * alpha),
                             f2bf((acc[m][n][2] + bv) * alpha),
                             f2bf((acc[m][n][3] + bv) * alpha) };
                *(U16x4*)&C[base] = pk;
            }
        }
    }
}

// ---------------------------------------------------------------------------
// Flash cross-attention, v2.
//   * 512 threads = 8 waves. Waves 0-3 = kv group 0 [0,2048), waves 4-7 =
//     group 1 [2048,4096). Wave w of each group owns q-rows q0 + w*16.
//     End-of-loop merge of (m, l, po) through LDS. Doubles waves/SIMD 2->4.
//   * K/V LDS tiles XOR-swizzled: global_load_lds source column chunk is
//     (lane&7)^(srow&7) (LDS dest stays linear, m173 pattern); reads XOR the
//     chunk index with row&7. Kills the 16-way bank conflict at stride 128B.
//   * Q pre-scaled by 0.125*log2(e) in its GEMM -> softmax uses exp2f raw.
//   * P packed with v_cvt_pk_bf16_f32 (RNE, same as f2bf).
//   * XCD-aware workgroup swizzle: 64 consecutive work items per XCD so each
//     XCD's L2 holds ~4 (b,h) K/V panels.
// Grid: 512 x 1 x 1 (decoded in-kernel), block 512.
// ---------------------------------------------------------------------------
__global__ __launch_bounds__(512)
void attn_fwd(const u16* __restrict__ Q, const u16* __restrict__ Kg,
              const u16* __restrict__ Vt, u16* __restrict__ O)
{
    constexpr int D = 1024, LDP = 72, CSTR = 19;
    __shared__ __align__(16) char smem[16384 + 16384 + 8 * 16 * LDP * 2];

    const int tid = threadIdx.x, wid = tid >> 6, lane = tid & 63;
    const int grp = wid >> 2, w = wid & 3;
    const int lr = lane & 15, lg = lane >> 4;
    const int rs = lr & 7;                       // read-side swizzle key

    // XCD swizzle: 512 wgs, 64 consecutive work items per XCD
    const int fid = blockIdx.x;
    const int wk = (fid & 7) * 64 + (fid >> 3);
    const int qblk = wk & 15, h = (wk >> 4) & 15, b = wk >> 8;
    const int q0 = qblk * 64 + w * 16;

    u16* sKg = (u16*)smem + grp * 4096;                  // [64][64] per group
    u16* sVg = (u16*)(smem + 16384) + grp * 4096;        // V^T tile [d][kv]
    u16* sPw = (u16*)(smem + 32768) + wid * 16 * LDP;
    float* cb = (float*)smem;                            // merge buffer (reuse)

    // Q fragments (Q pre-scaled by 0.125*log2e)
    const u16* Qrow = Q + (size_t)(b * 1024 + q0 + lr) * D + h * 64;
    const bf16x8 qf0 = *(const bf16x8*)(Qrow + lg * 8);
    const bf16x8 qf1 = *(const bf16x8*)(Qrow + 32 + lg * 8);

    // staging source (swizzled column chunk)
    const int srow = w * 8 + (lane >> 3);
    const int scol = (((lane & 7) ^ (srow & 7))) * 8;
    const u16* Kst = Kg + (size_t)(b * 4096 + grp * 2048 + srow) * D + h * 64 + scol;
    const u16* Vst = Vt + ((size_t)(b * 16 + h) * 64 + srow) * 4096 + grp * 2048 + scol;

    f32x4 po[4];
#pragma unroll
    for (int df = 0; df < 4; ++df) po[df] = (f32x4){0.f, 0.f, 0.f, 0.f};
    float m = -INFINITY, l = 0.f;

    for (int t = 0; t < 32; ++t) {
        const int kv0 = t * 64;
        __syncthreads();
        gload_lds16(Kst + (size_t)kv0 * D,         (char*)sKg + w * 1024);
        gload_lds16(Kst + (size_t)(kv0 + 32) * D,  (char*)sKg + 4096 + w * 1024);
        gload_lds16(Vst + kv0,                     (char*)sVg + w * 1024);
        gload_lds16(Vst + (size_t)32 * 4096 + kv0, (char*)sVg + 4096 + w * 1024);
        __syncthreads();

        // S^T[kv][q] = K . Q^T   (scores already in log2 domain)
        f32x4 s4[4];
#pragma unroll
        for (int f = 0; f < 4; ++f) {
            const int r = f * 16 + lr;
            bf16x8 k0v = *(const bf16x8*)&sKg[r * 64 + ((lg ^ rs)) * 8];
            bf16x8 k1v = *(const bf16x8*)&sKg[r * 64 + (((lg + 4) ^ rs)) * 8];
            f32x4 z = (f32x4){0.f, 0.f, 0.f, 0.f};
            z = __builtin_amdgcn_mfma_f32_16x16x32_bf16(k0v, qf0, z, 0, 0, 0);
            s4[f] = __builtin_amdgcn_mfma_f32_16x16x32_bf16(k1v, qf1, z, 0, 0, 0);
        }

        // online softmax (base-2); lane holds kv = 16f+4lg+j for q-col lr
        float tmax = s4[0][0];
#pragma unroll
        for (int f = 0; f < 4; ++f) {
            tmax = fmaxf(tmax, fmaxf(fmaxf(s4[f][0], s4[f][1]), fmaxf(s4[f][2], s4[f][3])));
        }
        tmax = fmaxf(tmax, __shfl_xor(tmax, 16, 64));
        tmax = fmaxf(tmax, __shfl_xor(tmax, 32, 64));
        const float mn = fmaxf(m, tmax);
        const float corr = exp2f(m - mn);
        float lsum = 0.f;
        uint2 pk[4];
#pragma unroll
        for (int f = 0; f < 4; ++f) {
            float p0 = exp2f(s4[f][0] - mn);
            float p1 = exp2f(s4[f][1] - mn);
            float p2 = exp2f(s4[f][2] - mn);
            float p3 = exp2f(s4[f][3] - mn);
            lsum += (p0 + p1) + (p2 + p3);
            pk[f].x = cvt_pk_bf16(p0, p1);
            pk[f].y = cvt_pk_bf16(p2, p3);
        }
        lsum += __shfl_xor(lsum, 16, 64);
        lsum += __shfl_xor(lsum, 32, 64);
        l = l * corr + lsum;
#pragma unroll
        for (int df = 0; df < 4; ++df) po[df] *= corr;
        m = mn;

        // P[q][kv] -> per-wave LDS strip (wave-private, DS ops in-order)
#pragma unroll
        for (int f = 0; f < 4; ++f)
            *(uint2*)&sPw[lr * LDP + f * 16 + lg * 4] = pk[f];

        // out^T[d][q] += V^T . P^T
#pragma unroll
        for (int c = 0; c < 2; ++c) {
            bf16x8 pf = *(const bf16x8*)&sPw[lr * LDP + c * 32 + lg * 8];
#pragma unroll
            for (int df = 0; df < 4; ++df) {
                const int r = df * 16 + lr;
                bf16x8 vf = *(const bf16x8*)&sVg[r * 64 + (((c * 4 + lg) ^ rs)) * 8];
                po[df] = __builtin_amdgcn_mfma_f32_16x16x32_bf16(vf, pf, po[df], 0, 0, 0);
            }
        }
    }

    // merge the two kv halves through LDS, then normalize + store (group 0)
    __syncthreads();
    if (grp == 1) {
        float* dst = cb + (size_t)(w * 64 + lane) * CSTR;
        dst[0] = m; dst[1] = l;
#pragma unroll
        for (int df = 0; df < 4; ++df)
#pragma unroll
            for (int j = 0; j < 4; ++j) dst[2 + df * 4 + j] = po[df][j];
    }
    __syncthreads();
    if (grp == 0) {
        const float* src = cb + (size_t)(w * 64 + lane) * CSTR;
        const float m1 = src[0], l1 = src[1];
        const float M = fmaxf(m, m1);
        const float c0 = exp2f(m - M), c1 = exp2f(m1 - M);
        const float rl = 1.f / (l * c0 + l1 * c1);
        u16* Orow = O + (size_t)(b * 1024 + q0 + lr) * D + h * 64;
#pragma unroll
        for (int df = 0; df < 4; ++df) {
            U16x4 pk = { f2bf((po[df][0] * c0 + src[2 + df * 4 + 0] * c1) * rl),
                         f2bf((po[df][1] * c0 + src[2 + df * 4 + 1] * c1) * rl),
                         f2bf((po[df][2] * c0 + src[2 + df * 4 + 2] * c1) * rl),
                         f2bf((po[df][3] * c0 + src[2 + df * 4 + 3] * c1) * rl) };
            *(U16x4*)&Orow[df * 16 + lg * 4] = pk;
        }
    }
}

// ---------------------------------------------------------------------------
extern "C" void kernel_launch(void* const* d_in, const int* in_sizes, int n_in,
                              void* d_out, int out_size, void* d_ws, size_t ws_size,
                              hipStream_t stream)
{
    const float* query   = (const float*)d_in[0];
    const float* context = (const float*)d_in[1];
    const float* wq = (const float*)d_in[2];
    const float* bq = (const float*)d_in[3];
    const float* wk = (const float*)d_in[4];
    const float* bk = (const float*)d_in[5];
    const float* wv = (const float*)d_in[6];
    const float* bv = (const float*)d_in[7];
    const float* wo = (const float*)d_in[8];
    const float* bo = (const float*)d_in[9];
    const float* g_q  = (const float*)d_in[10];
    const float* b_q  = (const float*)d_in[11];
    const float* g_kv = (const float*)d_in[12];
    const float* b_kv = (const float*)d_in[13];

    char* p = (char*)d_ws;
    auto alloc = [&](size_t bytes) { char* r = p; p += (bytes + 255) & ~(size_t)255; return r; };
    u16*   wqb  = (u16*)alloc(1024 * 1024 * 2);
    u16*   wkb  = (u16*)alloc(1024 * 1024 * 2);
    u16*   wvb  = (u16*)alloc(1024 * 1024 * 2);
    u16*   wob  = (u16*)alloc(1024 * 1024 * 2);
    float* qn32 = (float*)alloc((size_t)2048 * 1024 * 4);
    u16*   qnb  = (u16*)alloc((size_t)2048 * 1024 * 2);
    u16*   cnb  = (u16*)alloc((size_t)8192 * 1024 * 2);
    u16*   Qb   = (u16*)alloc((size_t)2048 * 1024 * 2);
    u16*   Kb   = (u16*)alloc((size_t)8192 * 1024 * 2);
    u16*   Vtb  = (u16*)alloc((size_t)8192 * 1024 * 2);
    u16*   AOb  = (u16*)alloc((size_t)2048 * 1024 * 2);

    wconv4<<<1024, 256, 0, stream>>>((const float4*)wq, (const float4*)wk,
                                     (const float4*)wv, (const float4*)wo,
                                     (U16x4*)wqb, (U16x4*)wkb, (U16x4*)wvb, (U16x4*)wob);
    ln_fused<<<512, 256, 0, stream>>>(query, g_q, b_q, qn32, qnb);
    ln_fused<<<2048, 256, 0, stream>>>(context, g_kv, b_kv, nullptr, cnb);

    // Q = (qn.wq^T + bq) * 0.125 * log2(e)  (attn scale + exp2 conversion folded)
    gemm_bt<0><<<dim3(16, 8), 256, 0, stream>>>(qnb, wqb, bq, nullptr, Qb, 2048, 1024, 1024, 0.18033688f);
    gemm_bt<0><<<dim3(64, 8), 256, 0, stream>>>(cnb, wkb, bk, nullptr, Kb, 8192, 1024, 1024, 1.0f);
    gemm_bt<2><<<dim3(64, 8), 256, 0, stream>>>(cnb, wvb, bv, nullptr, Vtb, 8192, 1024, 1024, 1.0f);

    attn_fwd<<<dim3(512), 512, 0, stream>>>(Qb, Kb, Vtb, AOb);

    // out = qn + AO.wo^T + bo   (f32 output, residual fused)
    gemm_bt<1><<<dim3(16, 8), 256, 0, stream>>>(AOb, wob, bo, qn32, d_out, 2048, 1024, 1024, 1.0f);
}

// Round 3
// 193.708 us; speedup vs baseline: 1.2531x; 1.0830x over previous
//
#include <hip/hip_runtime.h>

typedef unsigned short u16;
typedef __attribute__((ext_vector_type(8))) __bf16 bf16x8;
typedef __attribute__((ext_vector_type(4))) float f32x4;

struct alignas(8) U16x4 { u16 x, y, z, w; };

__device__ __forceinline__ u16 f2bf(float f) {
    union { float f; unsigned u; } v; v.f = f;
    unsigned r = v.u + 0x7fffu + ((v.u >> 16) & 1u);
    return (u16)(r >> 16);
}

__device__ __forceinline__ unsigned cvt_pk_bf16(float lo, float hi) {
    unsigned r;
    asm("v_cvt_pk_bf16_f32 %0, %1, %2" : "=v"(r) : "v"(lo), "v"(hi));
    return r;
}

__device__ __forceinline__ float fexp2(float x) {   // raw v_exp_f32 (2^x)
    float r;
    asm("v_exp_f32 %0, %1" : "=v"(r) : "v"(x));
    return r;
}

__device__ __forceinline__ void gload_lds16(const void* g, void* l) {
    __builtin_amdgcn_global_load_lds(
        (__attribute__((address_space(1))) void*)g,
        (__attribute__((address_space(3))) void*)l, 16, 0, 0);
}

// ---------------------------------------------------------------------------
// LayerNorm: one wave per row (D=1024). Writes optional f32 copy + bf16 copy.
// ---------------------------------------------------------------------------
__global__ __launch_bounds__(256)
void ln_fused(const float* __restrict__ x, const float* __restrict__ g,
              const float* __restrict__ be, float* __restrict__ y32,
              u16* __restrict__ y16)
{
    const int wid = threadIdx.x >> 6, lane = threadIdx.x & 63;
    const size_t row = (size_t)blockIdx.x * 4 + wid;
    const float4* xr = (const float4*)(x + row * 1024);
    float4 v[4];
    float s = 0.f, ss = 0.f;
#pragma unroll
    for (int i = 0; i < 4; ++i) {
        v[i] = xr[i * 64 + lane];
        s  += (v[i].x + v[i].y) + (v[i].z + v[i].w);
        ss += (v[i].x * v[i].x + v[i].y * v[i].y) + (v[i].z * v[i].z + v[i].w * v[i].w);
    }
#pragma unroll
    for (int o = 32; o; o >>= 1) { s += __shfl_xor(s, o, 64); ss += __shfl_xor(ss, o, 64); }
    const float mu = s * (1.f / 1024.f);
    const float rstd = rsqrtf(ss * (1.f / 1024.f) - mu * mu + 1e-5f);
#pragma unroll
    for (int i = 0; i < 4; ++i) {
        float4 gv = ((const float4*)g)[i * 64 + lane];
        float4 bv = ((const float4*)be)[i * 64 + lane];
        float4 o;
        o.x = (v[i].x - mu) * rstd * gv.x + bv.x;
        o.y = (v[i].y - mu) * rstd * gv.y + bv.y;
        o.z = (v[i].z - mu) * rstd * gv.z + bv.z;
        o.w = (v[i].w - mu) * rstd * gv.w + bv.w;
        if (y32) ((float4*)(y32 + row * 1024))[i * 64 + lane] = o;
        U16x4 pk = { f2bf(o.x), f2bf(o.y), f2bf(o.z), f2bf(o.w) };
        ((U16x4*)(y16 + row * 1024))[i * 64 + lane] = pk;
    }
}

// ---------------------------------------------------------------------------
// Weight conversion f32 -> bf16 for all four projection matrices.
// ---------------------------------------------------------------------------
__global__ __launch_bounds__(256)
void wconv4(const float4* __restrict__ a, const float4* __restrict__ b,
            const float4* __restrict__ c, const float4* __restrict__ d,
            U16x4* __restrict__ oa, U16x4* __restrict__ ob,
            U16x4* __restrict__ oc, U16x4* __restrict__ od)
{
    const int i = blockIdx.x * 256 + threadIdx.x;
    float4 v;
    v = a[i]; oa[i] = { f2bf(v.x), f2bf(v.y), f2bf(v.z), f2bf(v.w) };
    v = b[i]; ob[i] = { f2bf(v.x), f2bf(v.y), f2bf(v.z), f2bf(v.w) };
    v = c[i]; oc[i] = { f2bf(v.x), f2bf(v.y), f2bf(v.z), f2bf(v.w) };
    v = d[i]; od[i] = { f2bf(v.x), f2bf(v.y), f2bf(v.z), f2bf(v.w) };
}

// ---------------------------------------------------------------------------
// GEMM: C[m,n] = (sum_k A[m,k] * W[n,k] + bias[n]) * alpha  (+ resid, MODE 1)
// A: bf16 [M,K] row-major. W: bf16 [N,K] row-major (torch Linear layout).
// MODE 0: bf16 out [M,N].  MODE 1: f32 out [M,N] + f32 residual.
// MODE 2: bf16 out transposed for V: [(m>>12)*1024 + n][m & 4095] (B,H*64,Nc).
// ---------------------------------------------------------------------------
template<int MODE>
__global__ __launch_bounds__(256)
void gemm_bt(const u16* __restrict__ A, const u16* __restrict__ W,
             const float* __restrict__ bias, const float* __restrict__ resid,
             void* __restrict__ Cp, int M, int N, int K, float alpha)
{
    constexpr int BK = 64;
    __shared__ __align__(16) u16 sA[128 * BK];
    __shared__ __align__(16) u16 sB[128 * BK];
    const int tid = threadIdx.x, wid = tid >> 6, lane = tid & 63;
    const int lr = lane & 15, lg = lane >> 4;
    const int wr = wid >> 1, wc = wid & 1;
    const int row0 = blockIdx.x * 128, col0 = blockIdx.y * 128;
    const int srow = wid * 8 + (lane >> 3), scol = (lane & 7) * 8;

    const u16* Ag = A + (size_t)(row0 + srow) * K + scol;
    const u16* Wg = W + (size_t)(col0 + srow) * K + scol;

    f32x4 acc[4][4];
#pragma unroll
    for (int m = 0; m < 4; ++m)
#pragma unroll
        for (int n = 0; n < 4; ++n) acc[m][n] = (f32x4){0.f, 0.f, 0.f, 0.f};

    for (int k0 = 0; k0 < K; k0 += BK) {
        __syncthreads();
#pragma unroll
        for (int i = 0; i < 4; ++i)
            gload_lds16(Ag + (size_t)i * 32 * K + k0, (char*)sA + i * 4096 + wid * 1024);
#pragma unroll
        for (int i = 0; i < 4; ++i)
            gload_lds16(Wg + (size_t)i * 32 * K + k0, (char*)sB + i * 4096 + wid * 1024);
        __syncthreads();
#pragma unroll
        for (int kk = 0; kk < 2; ++kk) {
            bf16x8 af[4], bfr[4];
#pragma unroll
            for (int m = 0; m < 4; ++m)
                af[m] = *(const bf16x8*)&sA[(wr * 64 + m * 16 + lr) * BK + kk * 32 + lg * 8];
#pragma unroll
            for (int n = 0; n < 4; ++n)
                bfr[n] = *(const bf16x8*)&sB[(wc * 64 + n * 16 + lr) * BK + kk * 32 + lg * 8];
#pragma unroll
            for (int m = 0; m < 4; ++m)
#pragma unroll
                for (int n = 0; n < 4; ++n)
                    acc[m][n] = __builtin_amdgcn_mfma_f32_16x16x32_bf16(af[m], bfr[n], acc[m][n], 0, 0, 0);
        }
    }

#pragma unroll
    for (int m = 0; m < 4; ++m) {
#pragma unroll
        for (int n = 0; n < 4; ++n) {
            const int r = row0 + wr * 64 + m * 16 + lg * 4;
            const int c = col0 + wc * 64 + n * 16 + lr;
            const float bv = bias[c];
            if constexpr (MODE == 0) {
                u16* C = (u16*)Cp;
#pragma unroll
                for (int j = 0; j < 4; ++j)
                    C[(size_t)(r + j) * N + c] = f2bf((acc[m][n][j] + bv) * alpha);
            } else if constexpr (MODE == 1) {
                float* C = (float*)Cp;
#pragma unroll
                for (int j = 0; j < 4; ++j)
                    C[(size_t)(r + j) * N + c] =
                        (acc[m][n][j] + bv) * alpha + resid[(size_t)(r + j) * N + c];
            } else {
                u16* C = (u16*)Cp;
                const size_t base = ((size_t)(r >> 12) * 1024 + c) * 4096 + (r & 4095);
                U16x4 pk = { f2bf((acc[m][n][0] + bv) * alpha),
                             f2bf((acc[m][n][1] + bv) * alpha),
                             f2bf((acc[m][n][2] + bv) * alpha),
                             f2bf((acc[m][n][3] + bv) * alpha) };
                *(U16x4*)&C[base] = pk;
            }
        }
    }
}

// ---------------------------------------------------------------------------
// Flash cross-attention, v3.
//   * T3 2-phase: K/V double-buffered (32+32 KB); stage tile t+1 BEFORE
//     compute of tile t; single vmcnt(0) + raw s_barrier per tile (loads had
//     the whole compute phase to land -> drain ~free).
//   * VALU diet: raw v_exp_f32; defer-max (skip shfl-reduce/corr/po-rescale
//     when __all(pmax <= m)); per-lane l accumulation (end-reduce only).
//   * P strips un-padded + XOR-swizzled (^(lr&7)<<4 on byte offsets) -> 16KB;
//     total LDS 80KB = exactly 2 blocks/CU.
// Grid: 512 x 1 x 1, block 512 (8 waves: grp=kv-half, w=q-16-block).
// ---------------------------------------------------------------------------
__global__ __launch_bounds__(512, 4)
void attn_fwd(const u16* __restrict__ Q, const u16* __restrict__ Kg,
              const u16* __restrict__ Vt, u16* __restrict__ O)
{
    constexpr int D = 1024, CSTR = 19;
    __shared__ __align__(16) char smem[81920];   // K 32K | V 32K | P 16K

    const int tid = threadIdx.x, wid = tid >> 6, lane = tid & 63;
    const int grp = wid >> 2, w = wid & 3;
    const int lr = lane & 15, lg = lane >> 4;
    const int rs = lr & 7;
    const int pkey = (lr & 7) << 4;

    // XCD swizzle: 512 wgs, 64 consecutive work items per XCD
    const int fid = blockIdx.x;
    const int wk = (fid & 7) * 64 + (fid >> 3);
    const int qblk = wk & 15, h = (wk >> 4) & 15, b = wk >> 8;
    const int q0 = qblk * 64 + w * 16;

    // Q fragments (Q pre-scaled by 0.125*log2e in its GEMM)
    const u16* Qrow = Q + (size_t)(b * 1024 + q0 + lr) * D + h * 64;
    const bf16x8 qf0 = *(const bf16x8*)(Qrow + lg * 8);
    const bf16x8 qf1 = *(const bf16x8*)(Qrow + 32 + lg * 8);

    // staging source (swizzled column chunk), running pointers
    const int srow = w * 8 + (lane >> 3);
    const int scol = ((lane & 7) ^ (srow & 7)) * 8;
    const u16* kp = Kg + (size_t)(b * 4096 + grp * 2048 + srow) * D + h * 64 + scol;
    const u16* vp = Vt + ((size_t)(b * 16 + h) * 64 + srow) * 4096 + grp * 2048 + scol;

    char* sProw = smem + 65536 + wid * 2048 + lr * 128;

    f32x4 po[4];
#pragma unroll
    for (int df = 0; df < 4; ++df) po[df] = (f32x4){0.f, 0.f, 0.f, 0.f};
    float m = -INFINITY, l = 0.f;

    // prologue: stage tile 0 into buf 0
    {
        char* kd = smem + grp * 8192 + w * 1024;
        char* vd = smem + 32768 + grp * 8192 + w * 1024;
        gload_lds16(kp,                      kd);
        gload_lds16(kp + (size_t)32 * D,     kd + 4096);
        gload_lds16(vp,                      vd);
        gload_lds16(vp + (size_t)32 * 4096,  vd + 4096);
        kp += (size_t)64 * D; vp += 64;
    }
    asm volatile("s_waitcnt vmcnt(0)" ::: "memory");
    asm volatile("s_barrier" ::: "memory");

    for (int t = 0; t < 32; ++t) {
        const int cur = t & 1;
        if (t < 31) {   // stage t+1 into the other buffer (overlaps compute)
            char* kd = smem + (cur ^ 1) * 16384 + grp * 8192 + w * 1024;
            char* vd = smem + 32768 + (cur ^ 1) * 16384 + grp * 8192 + w * 1024;
            gload_lds16(kp,                      kd);
            gload_lds16(kp + (size_t)32 * D,     kd + 4096);
            gload_lds16(vp,                      vd);
            gload_lds16(vp + (size_t)32 * 4096,  vd + 4096);
            kp += (size_t)64 * D; vp += 64;
        }

        const u16* kb = (const u16*)(smem + cur * 16384 + grp * 8192);
        const u16* vb = (const u16*)(smem + 32768 + cur * 16384 + grp * 8192);

        // S^T[kv][q] = K . Q^T   (scores in log2 domain)
        f32x4 s4[4];
#pragma unroll
        for (int f = 0; f < 4; ++f) {
            const int r = f * 16 + lr;
            bf16x8 k0v = *(const bf16x8*)&kb[r * 64 + (lg ^ rs) * 8];
            bf16x8 k1v = *(const bf16x8*)&kb[r * 64 + ((lg + 4) ^ rs) * 8];
            f32x4 z = (f32x4){0.f, 0.f, 0.f, 0.f};
            z = __builtin_amdgcn_mfma_f32_16x16x32_bf16(k0v, qf0, z, 0, 0, 0);
            s4[f] = __builtin_amdgcn_mfma_f32_16x16x32_bf16(k1v, qf1, z, 0, 0, 0);
        }

        // defer-max online softmax (base-2)
        float pmax = fmaxf(fmaxf(fmaxf(s4[0][0], s4[0][1]), fmaxf(s4[0][2], s4[0][3])),
                     fmaxf(fmaxf(fmaxf(s4[1][0], s4[1][1]), fmaxf(s4[1][2], s4[1][3])),
                     fmaxf(fmaxf(fmaxf(s4[2][0], s4[2][1]), fmaxf(s4[2][2], s4[2][3])),
                           fmaxf(fmaxf(s4[3][0], s4[3][1]), fmaxf(s4[3][2], s4[3][3])))));
        if (!__all(pmax <= m)) {
            float tmax = fmaxf(pmax, __shfl_xor(pmax, 16, 64));
            tmax = fmaxf(tmax, __shfl_xor(tmax, 32, 64));
            const float mn = fmaxf(m, tmax);
            const float corr = fexp2(m - mn);
            l *= corr;
#pragma unroll
            for (int df = 0; df < 4; ++df) po[df] *= corr;
            m = mn;
        }
        float lsum = 0.f;
        uint2 pk[4];
#pragma unroll
        for (int f = 0; f < 4; ++f) {
            float p0 = fexp2(s4[f][0] - m);
            float p1 = fexp2(s4[f][1] - m);
            float p2 = fexp2(s4[f][2] - m);
            float p3 = fexp2(s4[f][3] - m);
            lsum += (p0 + p1) + (p2 + p3);
            pk[f].x = cvt_pk_bf16(p0, p1);
            pk[f].y = cvt_pk_bf16(p2, p3);
        }
        l += lsum;

        // P[q][kv] -> swizzled per-wave strip (wave-private, DS in-order)
#pragma unroll
        for (int f = 0; f < 4; ++f)
            *(uint2*)(sProw + ((f * 32 + lg * 8) ^ pkey)) = pk[f];

        // out^T[d][q] += V^T . P^T
#pragma unroll
        for (int c = 0; c < 2; ++c) {
            bf16x8 pf = *(const bf16x8*)(sProw + ((c * 64 + lg * 16) ^ pkey));
#pragma unroll
            for (int df = 0; df < 4; ++df) {
                const int r = df * 16 + lr;
                bf16x8 vf = *(const bf16x8*)&vb[r * 64 + ((c * 4 + lg) ^ rs) * 8];
                po[df] = __builtin_amdgcn_mfma_f32_16x16x32_bf16(vf, pf, po[df], 0, 0, 0);
            }
        }

        asm volatile("s_waitcnt vmcnt(0)" ::: "memory");   // t+1 loads landed
        asm volatile("s_barrier" ::: "memory");            // buffer handoff
    }

    // reduce per-lane l across the q-column
    l += __shfl_xor(l, 16, 64);
    l += __shfl_xor(l, 32, 64);

    // merge the two kv halves through LDS (K region is dead now)
    float* cb = (float*)smem;
    if (grp == 1) {
        float* dst = cb + (size_t)(w * 64 + lane) * CSTR;
        dst[0] = m; dst[1] = l;
#pragma unroll
        for (int df = 0; df < 4; ++df)
#pragma unroll
            for (int j = 0; j < 4; ++j) dst[2 + df * 4 + j] = po[df][j];
    }
    __syncthreads();
    if (grp == 0) {
        const float* src = cb + (size_t)(w * 64 + lane) * CSTR;
        const float m1 = src[0], l1 = src[1];
        const float M = fmaxf(m, m1);
        const float c0 = fexp2(m - M), c1 = fexp2(m1 - M);
        const float rl = 1.f / (l * c0 + l1 * c1);
        u16* Orow = O + (size_t)(b * 1024 + q0 + lr) * D + h * 64;
#pragma unroll
        for (int df = 0; df < 4; ++df) {
            U16x4 opk = { f2bf((po[df][0] * c0 + src[2 + df * 4 + 0] * c1) * rl),
                          f2bf((po[df][1] * c0 + src[2 + df * 4 + 1] * c1) * rl),
                          f2bf((po[df][2] * c0 + src[2 + df * 4 + 2] * c1) * rl),
                          f2bf((po[df][3] * c0 + src[2 + df * 4 + 3] * c1) * rl) };
            *(U16x4*)&Orow[df * 16 + lg * 4] = opk;
        }
    }
}

// ---------------------------------------------------------------------------
extern "C" void kernel_launch(void* const* d_in, const int* in_sizes, int n_in,
                              void* d_out, int out_size, void* d_ws, size_t ws_size,
                              hipStream_t stream)
{
    const float* query   = (const float*)d_in[0];
    const float* context = (const float*)d_in[1];
    const float* wq = (const float*)d_in[2];
    const float* bq = (const float*)d_in[3];
    const float* wk = (const float*)d_in[4];
    const float* bk = (const float*)d_in[5];
    const float* wv = (const float*)d_in[6];
    const float* bv = (const float*)d_in[7];
    const float* wo = (const float*)d_in[8];
    const float* bo = (const float*)d_in[9];
    const float* g_q  = (const float*)d_in[10];
    const float* b_q  = (const float*)d_in[11];
    const float* g_kv = (const float*)d_in[12];
    const float* b_kv = (const float*)d_in[13];

    char* p = (char*)d_ws;
    auto alloc = [&](size_t bytes) { char* r = p; p += (bytes + 255) & ~(size_t)255; return r; };
    u16*   wqb  = (u16*)alloc(1024 * 1024 * 2);
    u16*   wkb  = (u16*)alloc(1024 * 1024 * 2);
    u16*   wvb  = (u16*)alloc(1024 * 1024 * 2);
    u16*   wob  = (u16*)alloc(1024 * 1024 * 2);
    float* qn32 = (float*)alloc((size_t)2048 * 1024 * 4);
    u16*   qnb  = (u16*)alloc((size_t)2048 * 1024 * 2);
    u16*   cnb  = (u16*)alloc((size_t)8192 * 1024 * 2);
    u16*   Qb   = (u16*)alloc((size_t)2048 * 1024 * 2);
    u16*   Kb   = (u16*)alloc((size_t)8192 * 1024 * 2);
    u16*   Vtb  = (u16*)alloc((size_t)8192 * 1024 * 2);
    u16*   AOb  = (u16*)alloc((size_t)2048 * 1024 * 2);

    wconv4<<<1024, 256, 0, stream>>>((const float4*)wq, (const float4*)wk,
                                     (const float4*)wv, (const float4*)wo,
                                     (U16x4*)wqb, (U16x4*)wkb, (U16x4*)wvb, (U16x4*)wob);
    ln_fused<<<512, 256, 0, stream>>>(query, g_q, b_q, qn32, qnb);
    ln_fused<<<2048, 256, 0, stream>>>(context, g_kv, b_kv, nullptr, cnb);

    // Q = (qn.wq^T + bq) * 0.125 * log2(e)  (attn scale + exp2 conversion folded)
    gemm_bt<0><<<dim3(16, 8), 256, 0, stream>>>(qnb, wqb, bq, nullptr, Qb, 2048, 1024, 1024, 0.18033688f);
    gemm_bt<0><<<dim3(64, 8), 256, 0, stream>>>(cnb, wkb, bk, nullptr, Kb, 8192, 1024, 1024, 1.0f);
    gemm_bt<2><<<dim3(64, 8), 256, 0, stream>>>(cnb, wvb, bv, nullptr, Vtb, 8192, 1024, 1024, 1.0f);

    attn_fwd<<<dim3(512), 512, 0, stream>>>(Qb, Kb, Vtb, AOb);

    // out = qn + AO.wo^T + bo   (f32 output, residual fused)
    gemm_bt<1><<<dim3(16, 8), 256, 0, stream>>>(AOb, wob, bo, qn32, d_out, 2048, 1024, 1024, 1.0f);
}

// Round 4
// 169.320 us; speedup vs baseline: 1.4336x; 1.1440x over previous
//
#include <hip/hip_runtime.h>

typedef unsigned short u16;
typedef __attribute__((ext_vector_type(8))) __bf16 bf16x8;
typedef __attribute__((ext_vector_type(4))) float f32x4;

struct alignas(8) U16x4 { u16 x, y, z, w; };

__device__ __forceinline__ u16 f2bf(float f) {
    union { float f; unsigned u; } v; v.f = f;
    unsigned r = v.u + 0x7fffu + ((v.u >> 16) & 1u);
    return (u16)(r >> 16);
}

__device__ __forceinline__ unsigned cvt_pk_bf16(float lo, float hi) {
    unsigned r;
    asm("v_cvt_pk_bf16_f32 %0, %1, %2" : "=v"(r) : "v"(lo), "v"(hi));
    return r;
}

__device__ __forceinline__ float fexp2(float x) {   // raw v_exp_f32 (2^x)
    float r;
    asm("v_exp_f32 %0, %1" : "=v"(r) : "v"(x));
    return r;
}

__device__ __forceinline__ void gload_lds16(const void* g, void* l) {
    __builtin_amdgcn_global_load_lds(
        (__attribute__((address_space(1))) void*)g,
        (__attribute__((address_space(3))) void*)l, 16, 0, 0);
}

// ---------------------------------------------------------------------------
// LayerNorm: one wave per row (D=1024). Writes optional f32 copy + bf16 copy.
// ---------------------------------------------------------------------------
__global__ __launch_bounds__(256)
void ln_fused(const float* __restrict__ x, const float* __restrict__ g,
              const float* __restrict__ be, float* __restrict__ y32,
              u16* __restrict__ y16)
{
    const int wid = threadIdx.x >> 6, lane = threadIdx.x & 63;
    const size_t row = (size_t)blockIdx.x * 4 + wid;
    const float4* xr = (const float4*)(x + row * 1024);
    float4 v[4];
    float s = 0.f, ss = 0.f;
#pragma unroll
    for (int i = 0; i < 4; ++i) {
        v[i] = xr[i * 64 + lane];
        s  += (v[i].x + v[i].y) + (v[i].z + v[i].w);
        ss += (v[i].x * v[i].x + v[i].y * v[i].y) + (v[i].z * v[i].z + v[i].w * v[i].w);
    }
#pragma unroll
    for (int o = 32; o; o >>= 1) { s += __shfl_xor(s, o, 64); ss += __shfl_xor(ss, o, 64); }
    const float mu = s * (1.f / 1024.f);
    const float rstd = rsqrtf(ss * (1.f / 1024.f) - mu * mu + 1e-5f);
#pragma unroll
    for (int i = 0; i < 4; ++i) {
        float4 gv = ((const float4*)g)[i * 64 + lane];
        float4 bv = ((const float4*)be)[i * 64 + lane];
        float4 o;
        o.x = (v[i].x - mu) * rstd * gv.x + bv.x;
        o.y = (v[i].y - mu) * rstd * gv.y + bv.y;
        o.z = (v[i].z - mu) * rstd * gv.z + bv.z;
        o.w = (v[i].w - mu) * rstd * gv.w + bv.w;
        if (y32) ((float4*)(y32 + row * 1024))[i * 64 + lane] = o;
        U16x4 pk = { f2bf(o.x), f2bf(o.y), f2bf(o.z), f2bf(o.w) };
        ((U16x4*)(y16 + row * 1024))[i * 64 + lane] = pk;
    }
}

// ---------------------------------------------------------------------------
// Weight conversion f32 -> bf16 for all four projection matrices.
// ---------------------------------------------------------------------------
__global__ __launch_bounds__(256)
void wconv4(const float4* __restrict__ a, const float4* __restrict__ b,
            const float4* __restrict__ c, const float4* __restrict__ d,
            U16x4* __restrict__ oa, U16x4* __restrict__ ob,
            U16x4* __restrict__ oc, U16x4* __restrict__ od)
{
    const int i = blockIdx.x * 256 + threadIdx.x;
    float4 v;
    v = a[i]; oa[i] = { f2bf(v.x), f2bf(v.y), f2bf(v.z), f2bf(v.w) };
    v = b[i]; ob[i] = { f2bf(v.x), f2bf(v.y), f2bf(v.z), f2bf(v.w) };
    v = c[i]; oc[i] = { f2bf(v.x), f2bf(v.y), f2bf(v.z), f2bf(v.w) };
    v = d[i]; od[i] = { f2bf(v.x), f2bf(v.y), f2bf(v.z), f2bf(v.w) };
}

// ---------------------------------------------------------------------------
// Merged K+V projection GEMM. A=cnb [8192,1024] staged ONCE per tile; both
// weight tiles staged alongside; two accumulators. 512 thr = 8 waves (2x4 of
// 64x32 per output), tile 128x128, BK=64, LDS 48KB single-buffered.
// K out: row-major bf16 [8192,1024]. V out: transposed [(r>>12)*1024+c][r&4095].
// ---------------------------------------------------------------------------
__global__ __launch_bounds__(512, 4)
void gemm_kv(const u16* __restrict__ A, const u16* __restrict__ Wk,
             const u16* __restrict__ Wv, const float* __restrict__ bkp,
             const float* __restrict__ bvp, u16* __restrict__ Kout,
             u16* __restrict__ Vt)
{
    constexpr int K = 1024, N = 1024, BK = 64;
    __shared__ __align__(16) u16 sA[128 * BK];
    __shared__ __align__(16) u16 sK[128 * BK];
    __shared__ __align__(16) u16 sV[128 * BK];
    const int tid = threadIdx.x, wid = tid >> 6, lane = tid & 63;
    const int lr = lane & 15, lg = lane >> 4;
    const int wr = wid >> 2, wc = wid & 3;
    const int row0 = blockIdx.x * 128, col0 = blockIdx.y * 128;
    const int srow = wid * 8 + (lane >> 3), scol = (lane & 7) * 8;

    const u16* Ag = A  + (size_t)(row0 + srow) * K + scol;
    const u16* Kg = Wk + (size_t)(col0 + srow) * K + scol;
    const u16* Vg = Wv + (size_t)(col0 + srow) * K + scol;

    f32x4 ka[4][2], va[4][2];
#pragma unroll
    for (int m = 0; m < 4; ++m)
#pragma unroll
        for (int n = 0; n < 2; ++n) {
            ka[m][n] = (f32x4){0.f, 0.f, 0.f, 0.f};
            va[m][n] = (f32x4){0.f, 0.f, 0.f, 0.f};
        }

    for (int k0 = 0; k0 < K; k0 += BK) {
        __syncthreads();
#pragma unroll
        for (int i = 0; i < 2; ++i) {
            gload_lds16(Ag + (size_t)i * 64 * K + k0, (char*)sA + i * 8192 + wid * 1024);
            gload_lds16(Kg + (size_t)i * 64 * K + k0, (char*)sK + i * 8192 + wid * 1024);
            gload_lds16(Vg + (size_t)i * 64 * K + k0, (char*)sV + i * 8192 + wid * 1024);
        }
        __syncthreads();
#pragma unroll
        for (int kk = 0; kk < 2; ++kk) {
            bf16x8 af[4], bk[2], bv[2];
#pragma unroll
            for (int m = 0; m < 4; ++m)
                af[m] = *(const bf16x8*)&sA[(wr * 64 + m * 16 + lr) * BK + kk * 32 + lg * 8];
#pragma unroll
            for (int n = 0; n < 2; ++n) {
                bk[n] = *(const bf16x8*)&sK[(wc * 32 + n * 16 + lr) * BK + kk * 32 + lg * 8];
                bv[n] = *(const bf16x8*)&sV[(wc * 32 + n * 16 + lr) * BK + kk * 32 + lg * 8];
            }
#pragma unroll
            for (int m = 0; m < 4; ++m)
#pragma unroll
                for (int n = 0; n < 2; ++n) {
                    ka[m][n] = __builtin_amdgcn_mfma_f32_16x16x32_bf16(af[m], bk[n], ka[m][n], 0, 0, 0);
                    va[m][n] = __builtin_amdgcn_mfma_f32_16x16x32_bf16(af[m], bv[n], va[m][n], 0, 0, 0);
                }
        }
    }

#pragma unroll
    for (int m = 0; m < 4; ++m) {
#pragma unroll
        for (int n = 0; n < 2; ++n) {
            const int r = row0 + wr * 64 + m * 16 + lg * 4;
            const int c = col0 + wc * 32 + n * 16 + lr;
            const float kb = bkp[c], vb = bvp[c];
#pragma unroll
            for (int j = 0; j < 4; ++j)
                Kout[(size_t)(r + j) * N + c] = f2bf(ka[m][n][j] + kb);
            const size_t base = ((size_t)(r >> 12) * 1024 + c) * 4096 + (r & 4095);
            U16x4 pk = { f2bf(va[m][n][0] + vb), f2bf(va[m][n][1] + vb),
                         f2bf(va[m][n][2] + vb), f2bf(va[m][n][3] + vb) };
            *(U16x4*)&Vt[base] = pk;
        }
    }
}

// ---------------------------------------------------------------------------
// Q/O projection GEMM, 64x128 tile (grid M/64 x N/128 -> 256 blocks @ M=2048
// fills all CUs). 4 waves (2x2 of 32x64). MODE 0: bf16 out * alpha.
// MODE 1: f32 out + f32 residual.
// ---------------------------------------------------------------------------
template<int MODE>
__global__ __launch_bounds__(256)
void gemm_bt64(const u16* __restrict__ A, const u16* __restrict__ W,
               const float* __restrict__ bias, const float* __restrict__ resid,
               void* __restrict__ Cp, int M, int N, int K, float alpha)
{
    constexpr int BK = 64;
    __shared__ __align__(16) u16 sA[64 * BK];
    __shared__ __align__(16) u16 sB[128 * BK];
    const int tid = threadIdx.x, wid = tid >> 6, lane = tid & 63;
    const int lr = lane & 15, lg = lane >> 4;
    const int wr = wid >> 1, wc = wid & 1;
    const int row0 = blockIdx.x * 64, col0 = blockIdx.y * 128;
    const int srow = wid * 8 + (lane >> 3), scol = (lane & 7) * 8;

    const u16* Ag = A + (size_t)(row0 + srow) * K + scol;
    const u16* Wg = W + (size_t)(col0 + srow) * K + scol;

    f32x4 acc[2][4];
#pragma unroll
    for (int m = 0; m < 2; ++m)
#pragma unroll
        for (int n = 0; n < 4; ++n) acc[m][n] = (f32x4){0.f, 0.f, 0.f, 0.f};

    for (int k0 = 0; k0 < K; k0 += BK) {
        __syncthreads();
#pragma unroll
        for (int i = 0; i < 2; ++i)
            gload_lds16(Ag + (size_t)i * 32 * K + k0, (char*)sA + i * 4096 + wid * 1024);
#pragma unroll
        for (int i = 0; i < 4; ++i)
            gload_lds16(Wg + (size_t)i * 32 * K + k0, (char*)sB + i * 4096 + wid * 1024);
        __syncthreads();
#pragma unroll
        for (int kk = 0; kk < 2; ++kk) {
            bf16x8 af[2], bfr[4];
#pragma unroll
            for (int m = 0; m < 2; ++m)
                af[m] = *(const bf16x8*)&sA[(wr * 32 + m * 16 + lr) * BK + kk * 32 + lg * 8];
#pragma unroll
            for (int n = 0; n < 4; ++n)
                bfr[n] = *(const bf16x8*)&sB[(wc * 64 + n * 16 + lr) * BK + kk * 32 + lg * 8];
#pragma unroll
            for (int m = 0; m < 2; ++m)
#pragma unroll
                for (int n = 0; n < 4; ++n)
                    acc[m][n] = __builtin_amdgcn_mfma_f32_16x16x32_bf16(af[m], bfr[n], acc[m][n], 0, 0, 0);
        }
    }

#pragma unroll
    for (int m = 0; m < 2; ++m) {
#pragma unroll
        for (int n = 0; n < 4; ++n) {
            const int r = row0 + wr * 32 + m * 16 + lg * 4;
            const int c = col0 + wc * 64 + n * 16 + lr;
            const float bv = bias[c];
            if constexpr (MODE == 0) {
                u16* C = (u16*)Cp;
#pragma unroll
                for (int j = 0; j < 4; ++j)
                    C[(size_t)(r + j) * N + c] = f2bf((acc[m][n][j] + bv) * alpha);
            } else {
                float* C = (float*)Cp;
#pragma unroll
                for (int j = 0; j < 4; ++j)
                    C[(size_t)(r + j) * N + c] =
                        (acc[m][n][j] + bv) * alpha + resid[(size_t)(r + j) * N + c];
            }
        }
    }
}

// ---------------------------------------------------------------------------
// Flash cross-attention, v3 (unchanged from R3).
// ---------------------------------------------------------------------------
__global__ __launch_bounds__(512, 4)
void attn_fwd(const u16* __restrict__ Q, const u16* __restrict__ Kg,
              const u16* __restrict__ Vt, u16* __restrict__ O)
{
    constexpr int D = 1024, CSTR = 19;
    __shared__ __align__(16) char smem[81920];   // K 32K | V 32K | P 16K

    const int tid = threadIdx.x, wid = tid >> 6, lane = tid & 63;
    const int grp = wid >> 2, w = wid & 3;
    const int lr = lane & 15, lg = lane >> 4;
    const int rs = lr & 7;
    const int pkey = (lr & 7) << 4;

    const int fid = blockIdx.x;
    const int wk = (fid & 7) * 64 + (fid >> 3);
    const int qblk = wk & 15, h = (wk >> 4) & 15, b = wk >> 8;
    const int q0 = qblk * 64 + w * 16;

    const u16* Qrow = Q + (size_t)(b * 1024 + q0 + lr) * D + h * 64;
    const bf16x8 qf0 = *(const bf16x8*)(Qrow + lg * 8);
    const bf16x8 qf1 = *(const bf16x8*)(Qrow + 32 + lg * 8);

    const int srow = w * 8 + (lane >> 3);
    const int scol = ((lane & 7) ^ (srow & 7)) * 8;
    const u16* kp = Kg + (size_t)(b * 4096 + grp * 2048 + srow) * D + h * 64 + scol;
    const u16* vp = Vt + ((size_t)(b * 16 + h) * 64 + srow) * 4096 + grp * 2048 + scol;

    char* sProw = smem + 65536 + wid * 2048 + lr * 128;

    f32x4 po[4];
#pragma unroll
    for (int df = 0; df < 4; ++df) po[df] = (f32x4){0.f, 0.f, 0.f, 0.f};
    float m = -INFINITY, l = 0.f;

    {
        char* kd = smem + grp * 8192 + w * 1024;
        char* vd = smem + 32768 + grp * 8192 + w * 1024;
        gload_lds16(kp,                      kd);
        gload_lds16(kp + (size_t)32 * D,     kd + 4096);
        gload_lds16(vp,                      vd);
        gload_lds16(vp + (size_t)32 * 4096,  vd + 4096);
        kp += (size_t)64 * D; vp += 64;
    }
    asm volatile("s_waitcnt vmcnt(0)" ::: "memory");
    asm volatile("s_barrier" ::: "memory");

    for (int t = 0; t < 32; ++t) {
        const int cur = t & 1;
        if (t < 31) {
            char* kd = smem + (cur ^ 1) * 16384 + grp * 8192 + w * 1024;
            char* vd = smem + 32768 + (cur ^ 1) * 16384 + grp * 8192 + w * 1024;
            gload_lds16(kp,                      kd);
            gload_lds16(kp + (size_t)32 * D,     kd + 4096);
            gload_lds16(vp,                      vd);
            gload_lds16(vp + (size_t)32 * 4096,  vd + 4096);
            kp += (size_t)64 * D; vp += 64;
        }

        const u16* kb = (const u16*)(smem + cur * 16384 + grp * 8192);
        const u16* vb = (const u16*)(smem + 32768 + cur * 16384 + grp * 8192);

        f32x4 s4[4];
#pragma unroll
        for (int f = 0; f < 4; ++f) {
            const int r = f * 16 + lr;
            bf16x8 k0v = *(const bf16x8*)&kb[r * 64 + (lg ^ rs) * 8];
            bf16x8 k1v = *(const bf16x8*)&kb[r * 64 + ((lg + 4) ^ rs) * 8];
            f32x4 z = (f32x4){0.f, 0.f, 0.f, 0.f};
            z = __builtin_amdgcn_mfma_f32_16x16x32_bf16(k0v, qf0, z, 0, 0, 0);
            s4[f] = __builtin_amdgcn_mfma_f32_16x16x32_bf16(k1v, qf1, z, 0, 0, 0);
        }

        float pmax = fmaxf(fmaxf(fmaxf(s4[0][0], s4[0][1]), fmaxf(s4[0][2], s4[0][3])),
                     fmaxf(fmaxf(fmaxf(s4[1][0], s4[1][1]), fmaxf(s4[1][2], s4[1][3])),
                     fmaxf(fmaxf(fmaxf(s4[2][0], s4[2][1]), fmaxf(s4[2][2], s4[2][3])),
                           fmaxf(fmaxf(s4[3][0], s4[3][1]), fmaxf(s4[3][2], s4[3][3])))));
        if (!__all(pmax <= m)) {
            float tmax = fmaxf(pmax, __shfl_xor(pmax, 16, 64));
            tmax = fmaxf(tmax, __shfl_xor(tmax, 32, 64));
            const float mn = fmaxf(m, tmax);
            const float corr = fexp2(m - mn);
            l *= corr;
#pragma unroll
            for (int df = 0; df < 4; ++df) po[df] *= corr;
            m = mn;
        }
        float lsum = 0.f;
        uint2 pk[4];
#pragma unroll
        for (int f = 0; f < 4; ++f) {
            float p0 = fexp2(s4[f][0] - m);
            float p1 = fexp2(s4[f][1] - m);
            float p2 = fexp2(s4[f][2] - m);
            float p3 = fexp2(s4[f][3] - m);
            lsum += (p0 + p1) + (p2 + p3);
            pk[f].x = cvt_pk_bf16(p0, p1);
            pk[f].y = cvt_pk_bf16(p2, p3);
        }
        l += lsum;

#pragma unroll
        for (int f = 0; f < 4; ++f)
            *(uint2*)(sProw + ((f * 32 + lg * 8) ^ pkey)) = pk[f];

#pragma unroll
        for (int c = 0; c < 2; ++c) {
            bf16x8 pf = *(const bf16x8*)(sProw + ((c * 64 + lg * 16) ^ pkey));
#pragma unroll
            for (int df = 0; df < 4; ++df) {
                const int r = df * 16 + lr;
                bf16x8 vf = *(const bf16x8*)&vb[r * 64 + ((c * 4 + lg) ^ rs) * 8];
                po[df] = __builtin_amdgcn_mfma_f32_16x16x32_bf16(vf, pf, po[df], 0, 0, 0);
            }
        }

        asm volatile("s_waitcnt vmcnt(0)" ::: "memory");
        asm volatile("s_barrier" ::: "memory");
    }

    l += __shfl_xor(l, 16, 64);
    l += __shfl_xor(l, 32, 64);

    float* cb = (float*)smem;
    if (grp == 1) {
        float* dst = cb + (size_t)(w * 64 + lane) * CSTR;
        dst[0] = m; dst[1] = l;
#pragma unroll
        for (int df = 0; df < 4; ++df)
#pragma unroll
            for (int j = 0; j < 4; ++j) dst[2 + df * 4 + j] = po[df][j];
    }
    __syncthreads();
    if (grp == 0) {
        const float* src = cb + (size_t)(w * 64 + lane) * CSTR;
        const float m1 = src[0], l1 = src[1];
        const float M = fmaxf(m, m1);
        const float c0 = fexp2(m - M), c1 = fexp2(m1 - M);
        const float rl = 1.f / (l * c0 + l1 * c1);
        u16* Orow = O + (size_t)(b * 1024 + q0 + lr) * D + h * 64;
#pragma unroll
        for (int df = 0; df < 4; ++df) {
            U16x4 opk = { f2bf((po[df][0] * c0 + src[2 + df * 4 + 0] * c1) * rl),
                          f2bf((po[df][1] * c0 + src[2 + df * 4 + 1] * c1) * rl),
                          f2bf((po[df][2] * c0 + src[2 + df * 4 + 2] * c1) * rl),
                          f2bf((po[df][3] * c0 + src[2 + df * 4 + 3] * c1) * rl) };
            *(U16x4*)&Orow[df * 16 + lg * 4] = opk;
        }
    }
}

// ---------------------------------------------------------------------------
extern "C" void kernel_launch(void* const* d_in, const int* in_sizes, int n_in,
                              void* d_out, int out_size, void* d_ws, size_t ws_size,
                              hipStream_t stream)
{
    const float* query   = (const float*)d_in[0];
    const float* context = (const float*)d_in[1];
    const float* wq = (const float*)d_in[2];
    const float* bq = (const float*)d_in[3];
    const float* wk = (const float*)d_in[4];
    const float* bk = (const float*)d_in[5];
    const float* wv = (const float*)d_in[6];
    const float* bv = (const float*)d_in[7];
    const float* wo = (const float*)d_in[8];
    const float* bo = (const float*)d_in[9];
    const float* g_q  = (const float*)d_in[10];
    const float* b_q  = (const float*)d_in[11];
    const float* g_kv = (const float*)d_in[12];
    const float* b_kv = (const float*)d_in[13];

    char* p = (char*)d_ws;
    auto alloc = [&](size_t bytes) { char* r = p; p += (bytes + 255) & ~(size_t)255; return r; };
    u16*   wqb  = (u16*)alloc(1024 * 1024 * 2);
    u16*   wkb  = (u16*)alloc(1024 * 1024 * 2);
    u16*   wvb  = (u16*)alloc(1024 * 1024 * 2);
    u16*   wob  = (u16*)alloc(1024 * 1024 * 2);
    float* qn32 = (float*)alloc((size_t)2048 * 1024 * 4);
    u16*   qnb  = (u16*)alloc((size_t)2048 * 1024 * 2);
    u16*   cnb  = (u16*)alloc((size_t)8192 * 1024 * 2);
    u16*   Qb   = (u16*)alloc((size_t)2048 * 1024 * 2);
    u16*   Kb   = (u16*)alloc((size_t)8192 * 1024 * 2);
    u16*   Vtb  = (u16*)alloc((size_t)8192 * 1024 * 2);
    u16*   AOb  = (u16*)alloc((size_t)2048 * 1024 * 2);

    wconv4<<<1024, 256, 0, stream>>>((const float4*)wq, (const float4*)wk,
                                     (const float4*)wv, (const float4*)wo,
                                     (U16x4*)wqb, (U16x4*)wkb, (U16x4*)wvb, (U16x4*)wob);
    ln_fused<<<512, 256, 0, stream>>>(query, g_q, b_q, qn32, qnb);
    ln_fused<<<2048, 256, 0, stream>>>(context, g_kv, b_kv, nullptr, cnb);

    // Q = (qn.wq^T + bq) * 0.125 * log2(e)  (attn scale + exp2 conversion folded)
    gemm_bt64<0><<<dim3(32, 8), 256, 0, stream>>>(qnb, wqb, bq, nullptr, Qb, 2048, 1024, 1024, 0.18033688f);
    // K row-major + V transposed, one pass over cnb
    gemm_kv<<<dim3(64, 8), 512, 0, stream>>>(cnb, wkb, wvb, bk, bv, Kb, Vtb);

    attn_fwd<<<dim3(512), 512, 0, stream>>>(Qb, Kb, Vtb, AOb);

    // out = qn + AO.wo^T + bo   (f32 output, residual fused)
    gemm_bt64<1><<<dim3(32, 8), 256, 0, stream>>>(AOb, wob, bo, qn32, d_out, 2048, 1024, 1024, 1.0f);
}

// Round 5
// 164.635 us; speedup vs baseline: 1.4744x; 1.0285x over previous
//
#include <hip/hip_runtime.h>

typedef unsigned short u16;
typedef __attribute__((ext_vector_type(8))) __bf16 bf16x8;
typedef __attribute__((ext_vector_type(4))) float f32x4;

struct alignas(8) U16x4 { u16 x, y, z, w; };

#define MFMA16(a, b, c) __builtin_amdgcn_mfma_f32_16x16x32_bf16(a, b, c, 0, 0, 0)

__device__ __forceinline__ u16 f2bf(float f) {
    union { float f; unsigned u; } v; v.f = f;
    unsigned r = v.u + 0x7fffu + ((v.u >> 16) & 1u);
    return (u16)(r >> 16);
}

__device__ __forceinline__ unsigned cvt_pk_bf16(float lo, float hi) {
    unsigned r;
    asm("v_cvt_pk_bf16_f32 %0, %1, %2" : "=v"(r) : "v"(lo), "v"(hi));
    return r;
}

__device__ __forceinline__ float fexp2(float x) {   // raw v_exp_f32 (2^x)
    float r;
    asm("v_exp_f32 %0, %1" : "=v"(r) : "v"(x));
    return r;
}

__device__ __forceinline__ void gload_lds16(const void* g, void* l) {
    __builtin_amdgcn_global_load_lds(
        (__attribute__((address_space(1))) void*)g,
        (__attribute__((address_space(3))) void*)l, 16, 0, 0);
}

// ---------------------------------------------------------------------------
// prep: fused LN(query)+LN(context)+weight-conversion. Grid 3584 x 256.
//   blocks [0,512):    LN query rows -> qn32 (f32) + qnb (bf16)
//   blocks [512,2560): LN context rows -> cnb (bf16)
//   blocks [2560,3584): f32->bf16 conversion of wq/wk/wv/wo
// ---------------------------------------------------------------------------
__global__ __launch_bounds__(256)
void prep(const float* __restrict__ query, const float* __restrict__ context,
          const float* __restrict__ g_q, const float* __restrict__ b_q,
          const float* __restrict__ g_kv, const float* __restrict__ b_kv,
          float* __restrict__ qn32, u16* __restrict__ qnb, u16* __restrict__ cnb,
          const float4* __restrict__ w0, const float4* __restrict__ w1,
          const float4* __restrict__ w2, const float4* __restrict__ w3,
          U16x4* __restrict__ o0, U16x4* __restrict__ o1,
          U16x4* __restrict__ o2, U16x4* __restrict__ o3)
{
    const int blk = blockIdx.x;
    if (blk < 2560) {
        const float *x, *g, *be; float* y32; u16* y16; int rb;
        if (blk < 512) { x = query;   g = g_q;  be = b_q;  y32 = qn32;    y16 = qnb; rb = blk; }
        else           { x = context; g = g_kv; be = b_kv; y32 = nullptr; y16 = cnb; rb = blk - 512; }
        const int wid = threadIdx.x >> 6, lane = threadIdx.x & 63;
        const size_t row = (size_t)rb * 4 + wid;
        const float4* xr = (const float4*)(x + row * 1024);
        float4 v[4];
        float s = 0.f, ss = 0.f;
#pragma unroll
        for (int i = 0; i < 4; ++i) {
            v[i] = xr[i * 64 + lane];
            s  += (v[i].x + v[i].y) + (v[i].z + v[i].w);
            ss += (v[i].x * v[i].x + v[i].y * v[i].y) + (v[i].z * v[i].z + v[i].w * v[i].w);
        }
#pragma unroll
        for (int o = 32; o; o >>= 1) { s += __shfl_xor(s, o, 64); ss += __shfl_xor(ss, o, 64); }
        const float mu = s * (1.f / 1024.f);
        const float rstd = rsqrtf(ss * (1.f / 1024.f) - mu * mu + 1e-5f);
#pragma unroll
        for (int i = 0; i < 4; ++i) {
            float4 gv = ((const float4*)g)[i * 64 + lane];
            float4 bv = ((const float4*)be)[i * 64 + lane];
            float4 o;
            o.x = (v[i].x - mu) * rstd * gv.x + bv.x;
            o.y = (v[i].y - mu) * rstd * gv.y + bv.y;
            o.z = (v[i].z - mu) * rstd * gv.z + bv.z;
            o.w = (v[i].w - mu) * rstd * gv.w + bv.w;
            if (y32) ((float4*)(y32 + row * 1024))[i * 64 + lane] = o;
            U16x4 pk = { f2bf(o.x), f2bf(o.y), f2bf(o.z), f2bf(o.w) };
            ((U16x4*)(y16 + row * 1024))[i * 64 + lane] = pk;
        }
    } else {
        const int i = (blk - 2560) * 256 + threadIdx.x;
        float4 v;
        v = w0[i]; o0[i] = { f2bf(v.x), f2bf(v.y), f2bf(v.z), f2bf(v.w) };
        v = w1[i]; o1[i] = { f2bf(v.x), f2bf(v.y), f2bf(v.z), f2bf(v.w) };
        v = w2[i]; o2[i] = { f2bf(v.x), f2bf(v.y), f2bf(v.z), f2bf(v.w) };
        v = w3[i]; o3[i] = { f2bf(v.x), f2bf(v.y), f2bf(v.z), f2bf(v.w) };
    }
}

// ---------------------------------------------------------------------------
// Merged K+V projection GEMM (unchanged from R4).
// ---------------------------------------------------------------------------
__global__ __launch_bounds__(512, 4)
void gemm_kv(const u16* __restrict__ A, const u16* __restrict__ Wk,
             const u16* __restrict__ Wv, const float* __restrict__ bkp,
             const float* __restrict__ bvp, u16* __restrict__ Kout,
             u16* __restrict__ Vt)
{
    constexpr int K = 1024, N = 1024, BK = 64;
    __shared__ __align__(16) u16 sA[128 * BK];
    __shared__ __align__(16) u16 sK[128 * BK];
    __shared__ __align__(16) u16 sV[128 * BK];
    const int tid = threadIdx.x, wid = tid >> 6, lane = tid & 63;
    const int lr = lane & 15, lg = lane >> 4;
    const int wr = wid >> 2, wc = wid & 3;
    const int row0 = blockIdx.x * 128, col0 = blockIdx.y * 128;
    const int srow = wid * 8 + (lane >> 3), scol = (lane & 7) * 8;

    const u16* Ag = A  + (size_t)(row0 + srow) * K + scol;
    const u16* Kg = Wk + (size_t)(col0 + srow) * K + scol;
    const u16* Vg = Wv + (size_t)(col0 + srow) * K + scol;

    f32x4 ka[4][2], va[4][2];
#pragma unroll
    for (int m = 0; m < 4; ++m)
#pragma unroll
        for (int n = 0; n < 2; ++n) {
            ka[m][n] = (f32x4){0.f, 0.f, 0.f, 0.f};
            va[m][n] = (f32x4){0.f, 0.f, 0.f, 0.f};
        }

    for (int k0 = 0; k0 < K; k0 += BK) {
        __syncthreads();
#pragma unroll
        for (int i = 0; i < 2; ++i) {
            gload_lds16(Ag + (size_t)i * 64 * K + k0, (char*)sA + i * 8192 + wid * 1024);
            gload_lds16(Kg + (size_t)i * 64 * K + k0, (char*)sK + i * 8192 + wid * 1024);
            gload_lds16(Vg + (size_t)i * 64 * K + k0, (char*)sV + i * 8192 + wid * 1024);
        }
        __syncthreads();
#pragma unroll
        for (int kk = 0; kk < 2; ++kk) {
            bf16x8 af[4], bk[2], bv[2];
#pragma unroll
            for (int m = 0; m < 4; ++m)
                af[m] = *(const bf16x8*)&sA[(wr * 64 + m * 16 + lr) * BK + kk * 32 + lg * 8];
#pragma unroll
            for (int n = 0; n < 2; ++n) {
                bk[n] = *(const bf16x8*)&sK[(wc * 32 + n * 16 + lr) * BK + kk * 32 + lg * 8];
                bv[n] = *(const bf16x8*)&sV[(wc * 32 + n * 16 + lr) * BK + kk * 32 + lg * 8];
            }
#pragma unroll
            for (int m = 0; m < 4; ++m)
#pragma unroll
                for (int n = 0; n < 2; ++n) {
                    ka[m][n] = MFMA16(af[m], bk[n], ka[m][n]);
                    va[m][n] = MFMA16(af[m], bv[n], va[m][n]);
                }
        }
    }

#pragma unroll
    for (int m = 0; m < 4; ++m) {
#pragma unroll
        for (int n = 0; n < 2; ++n) {
            const int r = row0 + wr * 64 + m * 16 + lg * 4;
            const int c = col0 + wc * 32 + n * 16 + lr;
            const float kb = bkp[c], vb = bvp[c];
#pragma unroll
            for (int j = 0; j < 4; ++j)
                Kout[(size_t)(r + j) * N + c] = f2bf(ka[m][n][j] + kb);
            const size_t base = ((size_t)(r >> 12) * 1024 + c) * 4096 + (r & 4095);
            U16x4 pk = { f2bf(va[m][n][0] + vb), f2bf(va[m][n][1] + vb),
                         f2bf(va[m][n][2] + vb), f2bf(va[m][n][3] + vb) };
            *(U16x4*)&Vt[base] = pk;
        }
    }
}

// ---------------------------------------------------------------------------
// Q/O projection GEMM, 64x128 tile (unchanged from R4).
// ---------------------------------------------------------------------------
template<int MODE>
__global__ __launch_bounds__(256)
void gemm_bt64(const u16* __restrict__ A, const u16* __restrict__ W,
               const float* __restrict__ bias, const float* __restrict__ resid,
               void* __restrict__ Cp, int M, int N, int K, float alpha)
{
    constexpr int BK = 64;
    __shared__ __align__(16) u16 sA[64 * BK];
    __shared__ __align__(16) u16 sB[128 * BK];
    const int tid = threadIdx.x, wid = tid >> 6, lane = tid & 63;
    const int lr = lane & 15, lg = lane >> 4;
    const int wr = wid >> 1, wc = wid & 1;
    const int row0 = blockIdx.x * 64, col0 = blockIdx.y * 128;
    const int srow = wid * 8 + (lane >> 3), scol = (lane & 7) * 8;

    const u16* Ag = A + (size_t)(row0 + srow) * K + scol;
    const u16* Wg = W + (size_t)(col0 + srow) * K + scol;

    f32x4 acc[2][4];
#pragma unroll
    for (int m = 0; m < 2; ++m)
#pragma unroll
        for (int n = 0; n < 4; ++n) acc[m][n] = (f32x4){0.f, 0.f, 0.f, 0.f};

    for (int k0 = 0; k0 < K; k0 += BK) {
        __syncthreads();
#pragma unroll
        for (int i = 0; i < 2; ++i)
            gload_lds16(Ag + (size_t)i * 32 * K + k0, (char*)sA + i * 4096 + wid * 1024);
#pragma unroll
        for (int i = 0; i < 4; ++i)
            gload_lds16(Wg + (size_t)i * 32 * K + k0, (char*)sB + i * 4096 + wid * 1024);
        __syncthreads();
#pragma unroll
        for (int kk = 0; kk < 2; ++kk) {
            bf16x8 af[2], bfr[4];
#pragma unroll
            for (int m = 0; m < 2; ++m)
                af[m] = *(const bf16x8*)&sA[(wr * 32 + m * 16 + lr) * BK + kk * 32 + lg * 8];
#pragma unroll
            for (int n = 0; n < 4; ++n)
                bfr[n] = *(const bf16x8*)&sB[(wc * 64 + n * 16 + lr) * BK + kk * 32 + lg * 8];
#pragma unroll
            for (int m = 0; m < 2; ++m)
#pragma unroll
                for (int n = 0; n < 4; ++n)
                    acc[m][n] = MFMA16(af[m], bfr[n], acc[m][n]);
        }
    }

#pragma unroll
    for (int m = 0; m < 2; ++m) {
#pragma unroll
        for (int n = 0; n < 4; ++n) {
            const int r = row0 + wr * 32 + m * 16 + lg * 4;
            const int c = col0 + wc * 64 + n * 16 + lr;
            const float bv = bias[c];
            if constexpr (MODE == 0) {
                u16* C = (u16*)Cp;
#pragma unroll
                for (int j = 0; j < 4; ++j)
                    C[(size_t)(r + j) * N + c] = f2bf((acc[m][n][j] + bv) * alpha);
            } else {
                float* C = (float*)Cp;
#pragma unroll
                for (int j = 0; j < 4; ++j)
                    C[(size_t)(r + j) * N + c] =
                        (acc[m][n][j] + bv) * alpha + resid[(size_t)(r + j) * N + c];
            }
        }
    }
}

// ---------------------------------------------------------------------------
// Flash cross-attention, v4: one-stage software pipeline (T15-style).
//   Iteration t: stage(t+1) || K ds_reads(t) || PV(t-1) from V-regs + P-strip
//   || QK^T(t) || softmax(t) || V(t)->regs. PV(t-1) and QK^T(t) are
//   independent MFMA chains; softmax VALU overlaps them. Single wave-private
//   P strip is safe: PV reads strip BEFORE softmax rewrites it (wave DS ops
//   are in-order). V(t) kept in 32 VGPRs so stage(t+1) may overwrite its LDS.
//   setprio(1) around the MFMA cluster (T5; phase-split now exists).
// ---------------------------------------------------------------------------
__global__ __launch_bounds__(512, 4)
void attn_fwd(const u16* __restrict__ Q, const u16* __restrict__ Kg,
              const u16* __restrict__ Vt, u16* __restrict__ O)
{
    constexpr int D = 1024, CSTR = 19;
    __shared__ __align__(16) char smem[81920];   // K 32K | V 32K | P 16K

    const int tid = threadIdx.x, wid = tid >> 6, lane = tid & 63;
    const int grp = wid >> 2, w = wid & 3;
    const int lr = lane & 15, lg = lane >> 4;
    const int rs = lr & 7;
    const int pkey = (lr & 7) << 4;

    const int fid = blockIdx.x;
    const int wkid = (fid & 7) * 64 + (fid >> 3);
    const int qblk = wkid & 15, h = (wkid >> 4) & 15, b = wkid >> 8;
    const int q0 = qblk * 64 + w * 16;

    const u16* Qrow = Q + (size_t)(b * 1024 + q0 + lr) * D + h * 64;
    const bf16x8 qf0 = *(const bf16x8*)(Qrow + lg * 8);
    const bf16x8 qf1 = *(const bf16x8*)(Qrow + 32 + lg * 8);

    const int srow = w * 8 + (lane >> 3);
    const int scol = ((lane & 7) ^ (srow & 7)) * 8;
    const u16* kp = Kg + (size_t)(b * 4096 + grp * 2048 + srow) * D + h * 64 + scol;
    const u16* vp = Vt + ((size_t)(b * 16 + h) * 64 + srow) * 4096 + grp * 2048 + scol;

    char* sProw = smem + 65536 + wid * 2048 + lr * 128;

    f32x4 po[4];
#pragma unroll
    for (int df = 0; df < 4; ++df) po[df] = (f32x4){0.f, 0.f, 0.f, 0.f};
    float m = -INFINITY, l = 0.f;
    bf16x8 vr0, vr1, vr2, vr3, vr4, vr5, vr6, vr7;   // V(t) fragments [c*4+df]

    auto pv_step = [&]() {
        bf16x8 pf0 = *(const bf16x8*)(sProw + ((lg * 16) ^ pkey));
        bf16x8 pf1 = *(const bf16x8*)(sProw + ((64 + lg * 16) ^ pkey));
        po[0] = MFMA16(vr0, pf0, po[0]);
        po[1] = MFMA16(vr1, pf0, po[1]);
        po[2] = MFMA16(vr2, pf0, po[2]);
        po[3] = MFMA16(vr3, pf0, po[3]);
        po[0] = MFMA16(vr4, pf1, po[0]);
        po[1] = MFMA16(vr5, pf1, po[1]);
        po[2] = MFMA16(vr6, pf1, po[2]);
        po[3] = MFMA16(vr7, pf1, po[3]);
    };

    // prologue: stage tile 0 into buf 0
    {
        char* kd = smem + grp * 8192 + w * 1024;
        char* vd = smem + 32768 + grp * 8192 + w * 1024;
        gload_lds16(kp,                      kd);
        gload_lds16(kp + (size_t)32 * D,     kd + 4096);
        gload_lds16(vp,                      vd);
        gload_lds16(vp + (size_t)32 * 4096,  vd + 4096);
        kp += (size_t)64 * D; vp += 64;
    }
    asm volatile("s_waitcnt vmcnt(0)" ::: "memory");
    asm volatile("s_barrier" ::: "memory");

    for (int t = 0; t < 32; ++t) {
        const int cur = t & 1;
        if (t < 31) {   // stage t+1 into the other buffer (overlaps compute)
            char* kd = smem + (cur ^ 1) * 16384 + grp * 8192 + w * 1024;
            char* vd = smem + 32768 + (cur ^ 1) * 16384 + grp * 8192 + w * 1024;
            gload_lds16(kp,                      kd);
            gload_lds16(kp + (size_t)32 * D,     kd + 4096);
            gload_lds16(vp,                      vd);
            gload_lds16(vp + (size_t)32 * 4096,  vd + 4096);
            kp += (size_t)64 * D; vp += 64;
        }

        const u16* kb = (const u16*)(smem + cur * 16384 + grp * 8192);
        const u16* vb = (const u16*)(smem + 32768 + cur * 16384 + grp * 8192);

        __builtin_amdgcn_s_setprio(1);
        if (t > 0) pv_step();          // PV(t-1): V-regs + P-strip, no LDS dep on t

        // QK^T(t): S^T[kv][q] = K . Q^T   (scores in log2 domain)
        f32x4 s4[4];
#pragma unroll
        for (int f = 0; f < 4; ++f) {
            const int r = f * 16 + lr;
            bf16x8 k0v = *(const bf16x8*)&kb[r * 64 + (lg ^ rs) * 8];
            bf16x8 k1v = *(const bf16x8*)&kb[r * 64 + ((lg + 4) ^ rs) * 8];
            f32x4 z = (f32x4){0.f, 0.f, 0.f, 0.f};
            z = MFMA16(k0v, qf0, z);
            s4[f] = MFMA16(k1v, qf1, z);
        }
        __builtin_amdgcn_s_setprio(0);

        // V(t) -> registers (consumed by PV next iteration / epilogue)
        vr0 = *(const bf16x8*)&vb[(0 * 16 + lr) * 64 + ((0 + lg) ^ rs) * 8];
        vr1 = *(const bf16x8*)&vb[(1 * 16 + lr) * 64 + ((0 + lg) ^ rs) * 8];
        vr2 = *(const bf16x8*)&vb[(2 * 16 + lr) * 64 + ((0 + lg) ^ rs) * 8];
        vr3 = *(const bf16x8*)&vb[(3 * 16 + lr) * 64 + ((0 + lg) ^ rs) * 8];
        vr4 = *(const bf16x8*)&vb[(0 * 16 + lr) * 64 + ((4 + lg) ^ rs) * 8];
        vr5 = *(const bf16x8*)&vb[(1 * 16 + lr) * 64 + ((4 + lg) ^ rs) * 8];
        vr6 = *(const bf16x8*)&vb[(2 * 16 + lr) * 64 + ((4 + lg) ^ rs) * 8];
        vr7 = *(const bf16x8*)&vb[(3 * 16 + lr) * 64 + ((4 + lg) ^ rs) * 8];

        // defer-max online softmax (base-2)
        float pmax = fmaxf(fmaxf(fmaxf(s4[0][0], s4[0][1]), fmaxf(s4[0][2], s4[0][3])),
                     fmaxf(fmaxf(fmaxf(s4[1][0], s4[1][1]), fmaxf(s4[1][2], s4[1][3])),
                     fmaxf(fmaxf(fmaxf(s4[2][0], s4[2][1]), fmaxf(s4[2][2], s4[2][3])),
                           fmaxf(fmaxf(s4[3][0], s4[3][1]), fmaxf(s4[3][2], s4[3][3])))));
        if (!__all(pmax <= m)) {
            float tmax = fmaxf(pmax, __shfl_xor(pmax, 16, 64));
            tmax = fmaxf(tmax, __shfl_xor(tmax, 32, 64));
            const float mn = fmaxf(m, tmax);
            const float corr = fexp2(m - mn);
            l *= corr;
#pragma unroll
            for (int df = 0; df < 4; ++df) po[df] *= corr;
            m = mn;
        }
        float lsum = 0.f;
        uint2 pk[4];
#pragma unroll
        for (int f = 0; f < 4; ++f) {
            float p0 = fexp2(s4[f][0] - m);
            float p1 = fexp2(s4[f][1] - m);
            float p2 = fexp2(s4[f][2] - m);
            float p3 = fexp2(s4[f][3] - m);
            lsum += (p0 + p1) + (p2 + p3);
            pk[f].x = cvt_pk_bf16(p0, p1);
            pk[f].y = cvt_pk_bf16(p2, p3);
        }
        l += lsum;

        // P(t) -> strip (AFTER pv_step's reads of P(t-1); wave DS in-order)
#pragma unroll
        for (int f = 0; f < 4; ++f)
            *(uint2*)(sProw + ((f * 32 + lg * 8) ^ pkey)) = pk[f];

        asm volatile("s_waitcnt vmcnt(0) lgkmcnt(0)" ::: "memory");
        asm volatile("s_barrier" ::: "memory");
    }

    pv_step();   // PV(31)

    // reduce per-lane l across the q-column
    l += __shfl_xor(l, 16, 64);
    l += __shfl_xor(l, 32, 64);

    // merge the two kv halves through LDS (K region is dead now)
    float* cb = (float*)smem;
    if (grp == 1) {
        float* dst = cb + (size_t)(w * 64 + lane) * CSTR;
        dst[0] = m; dst[1] = l;
#pragma unroll
        for (int df = 0; df < 4; ++df)
#pragma unroll
            for (int j = 0; j < 4; ++j) dst[2 + df * 4 + j] = po[df][j];
    }
    __syncthreads();
    if (grp == 0) {
        const float* src = cb + (size_t)(w * 64 + lane) * CSTR;
        const float m1 = src[0], l1 = src[1];
        const float M = fmaxf(m, m1);
        const float c0 = fexp2(m - M), c1 = fexp2(m1 - M);
        const float rl = 1.f / (l * c0 + l1 * c1);
        u16* Orow = O + (size_t)(b * 1024 + q0 + lr) * D + h * 64;
#pragma unroll
        for (int df = 0; df < 4; ++df) {
            U16x4 opk = { f2bf((po[df][0] * c0 + src[2 + df * 4 + 0] * c1) * rl),
                          f2bf((po[df][1] * c0 + src[2 + df * 4 + 1] * c1) * rl),
                          f2bf((po[df][2] * c0 + src[2 + df * 4 + 2] * c1) * rl),
                          f2bf((po[df][3] * c0 + src[2 + df * 4 + 3] * c1) * rl) };
            *(U16x4*)&Orow[df * 16 + lg * 4] = opk;
        }
    }
}

// ---------------------------------------------------------------------------
extern "C" void kernel_launch(void* const* d_in, const int* in_sizes, int n_in,
                              void* d_out, int out_size, void* d_ws, size_t ws_size,
                              hipStream_t stream)
{
    const float* query   = (const float*)d_in[0];
    const float* context = (const float*)d_in[1];
    const float* wq = (const float*)d_in[2];
    const float* bq = (const float*)d_in[3];
    const float* wk = (const float*)d_in[4];
    const float* bk = (const float*)d_in[5];
    const float* wv = (const float*)d_in[6];
    const float* bv = (const float*)d_in[7];
    const float* wo = (const float*)d_in[8];
    const float* bo = (const float*)d_in[9];
    const float* g_q  = (const float*)d_in[10];
    const float* b_q  = (const float*)d_in[11];
    const float* g_kv = (const float*)d_in[12];
    const float* b_kv = (const float*)d_in[13];

    char* p = (char*)d_ws;
    auto alloc = [&](size_t bytes) { char* r = p; p += (bytes + 255) & ~(size_t)255; return r; };
    u16*   wqb  = (u16*)alloc(1024 * 1024 * 2);
    u16*   wkb  = (u16*)alloc(1024 * 1024 * 2);
    u16*   wvb  = (u16*)alloc(1024 * 1024 * 2);
    u16*   wob  = (u16*)alloc(1024 * 1024 * 2);
    float* qn32 = (float*)alloc((size_t)2048 * 1024 * 4);
    u16*   qnb  = (u16*)alloc((size_t)2048 * 1024 * 2);
    u16*   cnb  = (u16*)alloc((size_t)8192 * 1024 * 2);
    u16*   Qb   = (u16*)alloc((size_t)2048 * 1024 * 2);
    u16*   Kb   = (u16*)alloc((size_t)8192 * 1024 * 2);
    u16*   Vtb  = (u16*)alloc((size_t)8192 * 1024 * 2);
    u16*   AOb  = (u16*)alloc((size_t)2048 * 1024 * 2);

    prep<<<3584, 256, 0, stream>>>(query, context, g_q, b_q, g_kv, b_kv,
                                   qn32, qnb, cnb,
                                   (const float4*)wq, (const float4*)wk,
                                   (const float4*)wv, (const float4*)wo,
                                   (U16x4*)wqb, (U16x4*)wkb, (U16x4*)wvb, (U16x4*)wob);

    // Q = (qn.wq^T + bq) * 0.125 * log2(e)  (attn scale + exp2 conversion folded)
    gemm_bt64<0><<<dim3(32, 8), 256, 0, stream>>>(qnb, wqb, bq, nullptr, Qb, 2048, 1024, 1024, 0.18033688f);
    // K row-major + V transposed, one pass over cnb
    gemm_kv<<<dim3(64, 8), 512, 0, stream>>>(cnb, wkb, wvb, bk, bv, Kb, Vtb);

    attn_fwd<<<dim3(512), 512, 0, stream>>>(Qb, Kb, Vtb, AOb);

    // out = qn + AO.wo^T + bo   (f32 output, residual fused)
    gemm_bt64<1><<<dim3(32, 8), 256, 0, stream>>>(AOb, wob, bo, qn32, d_out, 2048, 1024, 1024, 1.0f);
}